// Round 19
// baseline (2948.663 us; speedup 1.0000x reference)
//
#include <hip/hip_runtime.h>
#include <hip/hip_bf16.h>

#define V_ 32000
#define H_ 1024
#define NH_ 16
#define I_ 4096
#define L_ 8
#define B_ 2
#define S_ 2048
#define DH_ 64
#define M_ 4096   // B_*S_
#define QS_ 3072  // fused QKV row stride
#define NSP_ 2    // flash split-KV factor

typedef __attribute__((ext_vector_type(4))) float f32x4;
typedef __attribute__((ext_vector_type(8))) short s16x8;

#define BARRIER() do { asm volatile("" ::: "memory"); __builtin_amdgcn_s_barrier(); asm volatile("" ::: "memory"); } while (0)
#define SCHEDB()  __builtin_amdgcn_sched_barrier(0)

__device__ __forceinline__ unsigned short f2b(float f) {
  union { float f; unsigned u; } x; x.f = f;
  return (unsigned short)((x.u + 0x7FFFu + ((x.u >> 16) & 1u)) >> 16);
}

__device__ __forceinline__ void gl_lds16(const unsigned short* g, unsigned short* l) {
  __builtin_amdgcn_global_load_lds(
      (__attribute__((address_space(1))) const void*)g,
      (__attribute__((address_space(3))) void*)l, 16, 0, 0);
}

// ---------------- weight f32 -> bf16 flat convert ------------------------------
__global__ __launch_bounds__(256) void wcvt(const float* __restrict__ src,
                                            unsigned short* __restrict__ dst) {
  size_t i = ((size_t)blockIdx.x * 256 + threadIdx.x) * 4;
  float4 v = *(const float4*)(src + i);
  ushort4 b;
  b.x = f2b(v.x); b.y = f2b(v.y); b.z = f2b(v.z); b.w = f2b(v.w);
  *(ushort4*)(dst + i) = b;
}

// concat per-layer Wq|Wk|Wv (each [H][H]) -> dst [l][3H][H] bf16 (all layers)
__global__ __launch_bounds__(256) void qkvcat_all(const float* __restrict__ q,
                                                  const float* __restrict__ k,
                                                  const float* __restrict__ v,
                                                  unsigned short* __restrict__ dst) {
  size_t i = ((size_t)blockIdx.x * 256 + threadIdx.x) * 4;
  size_t l = i / (3u * H_ * H_);
  size_t r = i - l * (3u * H_ * H_);
  const float* s; size_t off;
  if (r < (size_t)H_ * H_)          { s = q; off = l * H_ * H_ + r; }
  else if (r < 2u * H_ * H_)        { s = k; off = l * H_ * H_ + r - (size_t)H_ * H_; }
  else                              { s = v; off = l * H_ * H_ + r - 2u * H_ * H_; }
  float4 vv = *(const float4*)(s + off);
  ushort4 b;
  b.x = f2b(vv.x); b.y = f2b(vv.y); b.z = f2b(vv.z); b.w = f2b(vv.w);
  *(ushort4*)(dst + i) = b;
}

// concat per-layer Wq|Wk|Wv for ONE layer -> dst [3H][H] bf16 (fallback path)
__global__ __launch_bounds__(256) void qkvcat(const float* __restrict__ q,
                                              const float* __restrict__ k,
                                              const float* __restrict__ v,
                                              unsigned short* __restrict__ dst) {
  int i = (blockIdx.x * 256 + threadIdx.x) * 4;
  const float* s; int off;
  if (i < H_ * H_)          { s = q; off = i; }
  else if (i < 2 * H_ * H_) { s = k; off = i - H_ * H_; }
  else                      { s = v; off = i - 2 * H_ * H_; }
  float4 vv = *(const float4*)(s + off);
  ushort4 b;
  b.x = f2b(vv.x); b.y = f2b(vv.y); b.z = f2b(vv.z); b.w = f2b(vv.w);
  *(ushort4*)(dst + i) = b;
}

// concat biases bq|bk|bv per layer -> [L][3H] f32
__global__ __launch_bounds__(256) void bcat(const float* __restrict__ bq,
                                            const float* __restrict__ bk,
                                            const float* __restrict__ bv,
                                            float* __restrict__ dst) {
  int i = blockIdx.x * 256 + threadIdx.x;       // L_*3*H_ total
  int l = i / (3 * H_), r = i - l * 3 * H_;
  int p = r >> 10, c = r & (H_ - 1);
  const float* s = (p == 0) ? bq : ((p == 1) ? bk : bv);
  dst[i] = s[l * H_ + c];
}

// ---------------- embedding: h = tok[ids] + pos, also bf16 copy ----------------
__global__ __launch_bounds__(256) void embed_kernel(
    const int* __restrict__ ids, const float* __restrict__ tok,
    const float* __restrict__ pos, float* __restrict__ h,
    unsigned short* __restrict__ xbf)
{
  int row = blockIdx.x;
  int c4 = threadIdx.x;
  int id = ids[row];
  int s = row & (S_ - 1);
  float4 tv = ((const float4*)(tok + (size_t)id * H_))[c4];
  float4 pv = ((const float4*)(pos + (size_t)s * H_))[c4];
  float4 v; v.x = tv.x + pv.x; v.y = tv.y + pv.y; v.z = tv.z + pv.z; v.w = tv.w + pv.w;
  ((float4*)(h + (size_t)row * H_))[c4] = v;
  ushort4 b; b.x = f2b(v.x); b.y = f2b(v.y); b.z = f2b(v.z); b.w = f2b(v.w);
  ((ushort4*)(xbf + (size_t)row * H_))[c4] = b;
}

// ---------------- 128x128 GEMM v2: dbuf, 1 barrier/K-step, chunk-XOR swizzle --
// EPI 0: f32 out + bias.  EPI 1: gelu(x+bias) -> bf16.  EPI 2: bias -> bf16.
// EPI 3: QKV fused: Q/K cols -> bf16 at stride N; V cols -> transposed into vt.
template<int EPI>
__global__ __launch_bounds__(256) void gemm_bt(
    const unsigned short* __restrict__ A, const unsigned short* __restrict__ Wb,
    const float* __restrict__ bias, float* __restrict__ outf,
    unsigned short* __restrict__ outb, unsigned short* __restrict__ vt,
    int M, int N, int K, int ksz)
{
  __shared__ unsigned short As[2][128][32];
  __shared__ unsigned short Bs[2][128][32];
  int t = threadIdx.x;
  int lane = t & 63, wid = t >> 6;
  int m0 = blockIdx.x * 128, n0 = blockIdx.y * 128;
  int z = blockIdx.z;
  int koff = z * ksz;
  const float* bz = (z == 0) ? bias : nullptr;
  if (EPI == 0) outf += (size_t)z * M * N;
  int wm = (wid >> 1) * 64, wn = (wid & 1) * 64;
  int fr = lane & 15, hi = lane >> 4;
  int lrow = lane >> 2;
  int lcolsw = (((lane & 3) ^ (lrow & 3)) * 8);  // inverse-swizzled source col
  int ke = ((hi ^ (fr & 3)) * 8);                // swizzled read col (elems)

  f32x4 acc[4][4] = {};

  const unsigned short* Abase = A  + (size_t)(m0 + wid * 32 + lrow) * K + lcolsw;
  const unsigned short* Bbase = Wb + (size_t)(n0 + wid * 32 + lrow) * K + lcolsw;

  auto stage = [&](int s, int k0) {
    gl_lds16(Abase + k0,                  &As[s][wid * 32][0]);
    gl_lds16(Abase + k0 + (size_t)16 * K, &As[s][wid * 32 + 16][0]);
    gl_lds16(Bbase + k0,                  &Bs[s][wid * 32][0]);
    gl_lds16(Bbase + k0 + (size_t)16 * K, &Bs[s][wid * 32 + 16][0]);
  };

  stage(0, koff);

  int cur = 0;
  for (int k0 = koff; k0 < koff + ksz; k0 += 32) {
    asm volatile("s_waitcnt vmcnt(0)" ::: "memory");   // tile cur landed
    BARRIER();
    if (k0 + 32 < koff + ksz) stage(cur ^ 1, k0 + 32); // full K-step of lead time
    SCHEDB();
    s16x8 af[4], bfr[4];
    #pragma unroll
    for (int i = 0; i < 4; ++i) af[i]  = *(const s16x8*)(&As[cur][wm + i * 16 + fr][ke]);
    #pragma unroll
    for (int j = 0; j < 4; ++j) bfr[j] = *(const s16x8*)(&Bs[cur][wn + j * 16 + fr][ke]);
    #pragma unroll
    for (int i = 0; i < 4; ++i)
      #pragma unroll
      for (int j = 0; j < 4; ++j)
        acc[i][j] = __builtin_amdgcn_mfma_f32_16x16x32_bf16(af[i], bfr[j], acc[i][j], 0, 0, 0);
    cur ^= 1;
  }

  int fq = lane >> 4;
  if (EPI == 3) {
    #pragma unroll
    for (int i = 0; i < 4; ++i) {
      #pragma unroll
      for (int j = 0; j < 4; ++j) {
        int col = n0 + wn + j * 16 + fr;
        int row0_ = m0 + wm + i * 16 + fq * 4;
        float bcol = bz ? bz[col] : 0.f;
        if (col < 2 * H_) {
          #pragma unroll
          for (int r = 0; r < 4; ++r)
            outb[(size_t)(row0_ + r) * N + col] = f2b(acc[i][j][r] + bcol);
        } else {
          int d = col - 2 * H_;
          int bh = (row0_ >> 11) * NH_ + (d >> 6);
          int s0 = row0_ & (S_ - 1);
          ushort4 pk;
          pk.x = f2b(acc[i][j][0] + bcol);
          pk.y = f2b(acc[i][j][1] + bcol);
          pk.z = f2b(acc[i][j][2] + bcol);
          pk.w = f2b(acc[i][j][3] + bcol);
          *(ushort4*)(vt + ((size_t)bh * DH_ + (d & 63)) * S_ + s0) = pk;
        }
      }
    }
    return;
  }
  #pragma unroll
  for (int i = 0; i < 4; ++i) {
    #pragma unroll
    for (int j = 0; j < 4; ++j) {
      #pragma unroll
      for (int r = 0; r < 4; ++r) {
        int row = m0 + wm + i * 16 + fq * 4 + r;
        int col = n0 + wn + j * 16 + fr;
        float v = acc[i][j][r] + (bz ? bz[col] : 0.f);
        if (EPI == 0) {
          outf[(size_t)row * N + col] = v;
        } else if (EPI == 1) {
          float ge = 0.5f * v * (1.0f + erff(v * 0.70710678118f));
          outb[(size_t)row * N + col] = f2b(ge);
        } else {
          outb[(size_t)row * N + col] = f2b(v);
        }
      }
    }
  }
}

// ---------------- 256x256 GEMM (r8-proven config: distributed staging) --------
template<int EPI>
__global__ __launch_bounds__(512, 2) void gemm256(
    const unsigned short* __restrict__ A, const unsigned short* __restrict__ Wb,
    const float* __restrict__ bias, float* __restrict__ outf,
    unsigned short* __restrict__ outb, int M, int N, int K)
{
  __shared__ unsigned short ASm[2][16384];   // [slot][256 rows x 64 k]
  __shared__ unsigned short BSm[2][16384];

  const int t = threadIdx.x;
  const int lane = t & 63, wid = t >> 6;
  const int wm = wid >> 2, wn = wid & 3;          // 2 x 4 wave grid
  const int fr = lane & 15, hi = lane >> 4;

  const int Nt = N >> 8;
  const int nwg = gridDim.x;
  const int cpx = nwg >> 3;
  int bid = (int)blockIdx.x;
  int swz = (bid & 7) * cpx + (bid >> 3);
  int band = swz / (4 * Nt);
  int rem = swz - band * (4 * Nt);
  const int m0 = (band * 4 + (rem & 3)) << 8;
  const int n0 = (rem >> 2) << 8;

  const int NT = K >> 6;

  const int srow = lane >> 3;
  const int scol = ((lane & 7) ^ srow) << 3;
  const int ch0 = wid * 2;

  const int axorb = (fr & 7) << 4;
  const int koe0 = ((hi * 16) ^ axorb) >> 1;
  const int koe1 = (((hi * 16) | 64) ^ axorb) >> 1;

  f32x4 acc[8][4] = {};

  auto stage_half = [&](int slot, int h, int k0) {
    if (h < 2) {
      const unsigned short* src =
          A + (size_t)(m0 + h * 128 + ch0 * 8 + srow) * K + k0 + scol;
      unsigned short* dst = &ASm[slot][(h * 128 + ch0 * 8) * 64];
      gl_lds16(src, dst);
      gl_lds16(src + (size_t)8 * K, dst + 8 * 64);
    } else {
      const unsigned short* src =
          Wb + (size_t)(n0 + (h - 2) * 128 + ch0 * 8 + srow) * K + k0 + scol;
      unsigned short* dst = &BSm[slot][((h - 2) * 128 + ch0 * 8) * 64];
      gl_lds16(src, dst);
      gl_lds16(src + (size_t)8 * K, dst + 8 * 64);
    }
  };

  // prologue: tile0 -> slot0 (B first for HBM cover, then A)
  stage_half(0, 2, 0); stage_half(0, 3, 0); stage_half(0, 0, 0); stage_half(0, 1, 0);

  s16x8 af0[4][2], af1[4][2], bfv[4][2];

  for (int T = 0; T < NT; ++T) {
    const int s = T & 1;
    const int k1 = (T + 1) << 6;
    const bool more = (T + 1 < NT);

    asm volatile("s_waitcnt vmcnt(0)" ::: "memory");   // tile T fully landed
    BARRIER();

    const unsigned short* As_ = ASm[s];
    const unsigned short* Bs_ = BSm[s];

    // ---- R0: af0 (m0-3) + all bfv ; stage B-half0(T+1) ----
    #pragma unroll
    for (int mi = 0; mi < 4; ++mi) {
      const unsigned short* p = As_ + (wm * 128 + mi * 16 + fr) * 64;
      af0[mi][0] = *(const s16x8*)(p + koe0);
      af0[mi][1] = *(const s16x8*)(p + koe1);
    }
    #pragma unroll
    for (int nj = 0; nj < 4; ++nj) {
      const unsigned short* p = Bs_ + (wn * 64 + nj * 16 + fr) * 64;
      bfv[nj][0] = *(const s16x8*)(p + koe0);
      bfv[nj][1] = *(const s16x8*)(p + koe1);
    }
    if (more) stage_half(s ^ 1, 2, k1);
    SCHEDB();
    __builtin_amdgcn_s_setprio(1);
    #pragma unroll
    for (int mi = 0; mi < 4; ++mi)
      #pragma unroll
      for (int nj = 0; nj < 2; ++nj) {
        acc[mi][nj] = __builtin_amdgcn_mfma_f32_16x16x32_bf16(af0[mi][0], bfv[nj][0], acc[mi][nj], 0, 0, 0);
        acc[mi][nj] = __builtin_amdgcn_mfma_f32_16x16x32_bf16(af0[mi][1], bfv[nj][1], acc[mi][nj], 0, 0, 0);
      }
    __builtin_amdgcn_s_setprio(0);
    SCHEDB();

    // ---- R2: af1 (m4-7) ; stage B-half1(T+1) ----
    #pragma unroll
    for (int mi = 0; mi < 4; ++mi) {
      const unsigned short* p = As_ + (wm * 128 + (mi + 4) * 16 + fr) * 64;
      af1[mi][0] = *(const s16x8*)(p + koe0);
      af1[mi][1] = *(const s16x8*)(p + koe1);
    }
    if (more) stage_half(s ^ 1, 3, k1);
    SCHEDB();
    __builtin_amdgcn_s_setprio(1);
    #pragma unroll
    for (int mi = 0; mi < 4; ++mi)
      #pragma unroll
      for (int nj = 2; nj < 4; ++nj) {
        acc[mi][nj] = __builtin_amdgcn_mfma_f32_16x16x32_bf16(af0[mi][0], bfv[nj][0], acc[mi][nj], 0, 0, 0);
        acc[mi][nj] = __builtin_amdgcn_mfma_f32_16x16x32_bf16(af0[mi][1], bfv[nj][1], acc[mi][nj], 0, 0, 0);
      }
    __builtin_amdgcn_s_setprio(0);
    SCHEDB();

    // ---- stage A-half0(T+1) ; G2: m4-7 x n2-3 ----
    if (more) stage_half(s ^ 1, 0, k1);
    SCHEDB();
    __builtin_amdgcn_s_setprio(1);
    #pragma unroll
    for (int mi = 0; mi < 4; ++mi)
      #pragma unroll
      for (int nj = 2; nj < 4; ++nj) {
        acc[mi + 4][nj] = __builtin_amdgcn_mfma_f32_16x16x32_bf16(af1[mi][0], bfv[nj][0], acc[mi + 4][nj], 0, 0, 0);
        acc[mi + 4][nj] = __builtin_amdgcn_mfma_f32_16x16x32_bf16(af1[mi][1], bfv[nj][1], acc[mi + 4][nj], 0, 0, 0);
      }
    __builtin_amdgcn_s_setprio(0);
    SCHEDB();

    // ---- stage A-half1(T+1) ; G3: m4-7 x n0-1 ----
    if (more) stage_half(s ^ 1, 1, k1);
    SCHEDB();
    __builtin_amdgcn_s_setprio(1);
    #pragma unroll
    for (int mi = 0; mi < 4; ++mi)
      #pragma unroll
      for (int nj = 0; nj < 2; ++nj) {
        acc[mi + 4][nj] = __builtin_amdgcn_mfma_f32_16x16x32_bf16(af1[mi][0], bfv[nj][0], acc[mi + 4][nj], 0, 0, 0);
        acc[mi + 4][nj] = __builtin_amdgcn_mfma_f32_16x16x32_bf16(af1[mi][1], bfv[nj][1], acc[mi + 4][nj], 0, 0, 0);
      }
    __builtin_amdgcn_s_setprio(0);
  }

  #pragma unroll
  for (int mi = 0; mi < 8; ++mi) {
    #pragma unroll
    for (int nj = 0; nj < 4; ++nj) {
      #pragma unroll
      for (int r = 0; r < 4; ++r) {
        int row = m0 + wm * 128 + mi * 16 + hi * 4 + r;
        int col = n0 + wn * 64 + nj * 16 + fr;
        float v = acc[mi][nj][r] + (bias ? bias[col] : 0.f);
        if (EPI == 0) {
          outf[(size_t)row * N + col] = v;
        } else if (EPI == 1) {
          float ge = 0.5f * v * (1.0f + erff(v * 0.70710678118f));
          outb[(size_t)row * N + col] = f2b(ge);
        } else {
          outb[(size_t)row * N + col] = f2b(v);
        }
      }
    }
  }
}

// ---------------- MFMA flash attention v7 (r17 equal-best config) -------------
#define KB_ 64
#define SPL_ 1024
__global__ __launch_bounds__(512, 2) void flash_mfma(
    const unsigned short* __restrict__ qb,  // q slice base (stride QS_)
    const unsigned short* __restrict__ kb,  // k slice base (stride QS_)
    const unsigned short* __restrict__ vtb, // [B*NH][DH][S] bf16
    const float* __restrict__ mask,         // [B][S]
    float* __restrict__ opart,              // [NSP_][M][H] unnormalized
    float2* __restrict__ ml)                // [NSP_][32][S] (m, l)
{
  __shared__ unsigned short K2[2][KB_ * DH_];   // [slot][kv][d] swizzled
  __shared__ unsigned short V2[2][DH_ * KB_];   // [slot][d][kv] swizzled
  __shared__ unsigned short Ps[8][16][72];      // per-wave P [q][kv], padded
  __shared__ float xpose[8][16];                // per-wave q-transpose bounce

  const float LOG2E = 1.4426950408889634f;
  const float SCL = 0.125f * LOG2E;
  int t = threadIdx.x, lane = t & 63, wid = t >> 6;   // wid 0..7
  int blk = blockIdx.x;
  int bh = blk & 31;                    // bh fastest => same head -> same XCD
  int rest = blk >> 5;
  int qt = rest & 15, sp = rest >> 4;   // sp 0..1
  int b = bh >> 4, hh = bh & 15;
  int row0 = b * S_ + qt * 128 + wid * 16;
  int fr = lane & 15, hi = lane >> 4;
  const float* mrow = mask + (size_t)b * S_;
  const int kv0 = sp * SPL_;

  s16x8 qf[2];
  {
    const unsigned short* qrow = qb + (size_t)(row0 + fr) * QS_ + hh * DH_;
    qf[0] = *(const s16x8*)(qrow + hi * 8);
    qf[1] = *(const s16x8*)(qrow + 32 + hi * 8);
  }

  float m_run = -3.0e38f, l_run = 0.f;   // per q=fr (replicated over hi)
  f32x4 octx[4] = {};

  const unsigned short* Kbase = kb + (size_t)b * S_ * QS_ + hh * DH_;
  const unsigned short* Vbase = vtb + (size_t)bh * DH_ * S_;

  int crow = lane >> 3;
  int scol = ((lane & 7) ^ crow) * 8;

  auto stage = [&](int slot, int t0) {
    gl_lds16(Kbase + (size_t)(t0 + wid * 8 + crow) * QS_ + scol, &K2[slot][wid * 512]);
    gl_lds16(Vbase + (size_t)(wid * 8 + crow) * S_ + t0 + scol,  &V2[slot][wid * 512]);
  };

  stage(0, kv0);

  const int swz = (fr & 7) * 8;

  int tt = 0;
  for (int t0 = kv0; t0 < kv0 + SPL_; t0 += KB_, ++tt) {
    int slot = tt & 1;
    __syncthreads();
    if (t0 + KB_ < kv0 + SPL_) stage(slot ^ 1, t0 + KB_);

    // QK^T swapped: sacc[g] = mfma(K rows, Q) -> C[m=kv][n=q]
    f32x4 sacc[4] = {};
    #pragma unroll
    for (int g = 0; g < 4; ++g) {
      #pragma unroll
      for (int i = 0; i < 2; ++i) {
        s16x8 kf = *(const s16x8*)(&K2[slot][(g * 16 + fr) * 64 + ((i * 32 + hi * 8) ^ swz)]);
        sacc[g] = __builtin_amdgcn_mfma_f32_16x16x32_bf16(kf, qf[i], sacc[g], 0, 0, 0);
      }
    }

    // scale + mask in place; track tile max
    float tm = -3.0e38f;
    #pragma unroll
    for (int g = 0; g < 4; ++g) {
      float4 mq = *(const float4*)(mrow + t0 + g * 16 + hi * 4);
      #pragma unroll
      for (int r = 0; r < 4; ++r) {
        float mk = (1.0f - ((const float*)&mq)[r]) * (-10000.0f * LOG2E);
        float v = sacc[g][r] * SCL + mk;
        sacc[g][r] = v;
        tm = fmaxf(tm, v);
      }
    }
    tm = fmaxf(tm, __shfl_xor(tm, 16));
    tm = fmaxf(tm, __shfl_xor(tm, 32));

    if (!__all(tm <= m_run + 8.0f)) {
      float mn = fmaxf(m_run, tm);
      float corr = exp2f(m_run - mn);
      m_run = mn; l_run *= corr;
      xpose[wid][fr] = corr;
      float cr0 = xpose[wid][hi * 4 + 0];
      float cr1 = xpose[wid][hi * 4 + 1];
      float cr2 = xpose[wid][hi * 4 + 2];
      float cr3 = xpose[wid][hi * 4 + 3];
      #pragma unroll
      for (int dg = 0; dg < 4; ++dg) {
        octx[dg][0] *= cr0; octx[dg][1] *= cr1;
        octx[dg][2] *= cr2; octx[dg][3] *= cr3;
      }
    }

    // exp + pack + stream to Ps per group (short live ranges)
    float ps = 0.f;
    #pragma unroll
    for (int g = 0; g < 4; ++g) {
      float p0 = exp2f(sacc[g][0] - m_run);
      float p1 = exp2f(sacc[g][1] - m_run);
      float p2 = exp2f(sacc[g][2] - m_run);
      float p3 = exp2f(sacc[g][3] - m_run);
      ps += (p0 + p1) + (p2 + p3);
      uint2 pk;
      pk.x = (unsigned)f2b(p0) | ((unsigned)f2b(p1) << 16);
      pk.y = (unsigned)f2b(p2) | ((unsigned)f2b(p3) << 16);
      *(uint2*)(&Ps[wid][fr][g * 16 + hi * 4]) = pk;
    }
    ps += __shfl_xor(ps, 16);
    ps += __shfl_xor(ps, 32);
    l_run += ps;

    #pragma unroll
    for (int kc = 0; kc < 2; ++kc) {
      s16x8 pf = *(const s16x8*)(&Ps[wid][fr][kc * 32 + hi * 8]);
      #pragma unroll
      for (int dg = 0; dg < 4; ++dg) {
        s16x8 vf2 = *(const s16x8*)(&V2[slot][(dg * 16 + fr) * 64 + ((kc * 32 + hi * 8) ^ swz)]);
        octx[dg] = __builtin_amdgcn_mfma_f32_16x16x32_bf16(pf, vf2, octx[dg], 0, 0, 0);
      }
    }
  }

  float* ob = opart + (size_t)sp * M_ * H_;
  #pragma unroll
  for (int dg = 0; dg < 4; ++dg) {
    size_t base = (size_t)(row0 + hi * 4) * H_ + hh * DH_ + dg * 16 + fr;
    ob[base]          = octx[dg][0];
    ob[base + H_]     = octx[dg][1];
    ob[base + 2 * H_] = octx[dg][2];
    ob[base + 3 * H_] = octx[dg][3];
  }
  if (hi == 0)
    ml[((size_t)sp * 32 + bh) * S_ + qt * 128 + wid * 16 + fr] =
        make_float2(m_run, l_run);
}

// -------- fused 2-way attn-merge + residual + LayerNorm (POST-LN) -------------
__global__ __launch_bounds__(256) void add_ln_mrg(
    const float* __restrict__ x, const float* __restrict__ o0,
    const float* __restrict__ o1, const float2* __restrict__ ml,
    const float* __restrict__ g, const float* __restrict__ bb,
    float* __restrict__ outf, unsigned short* __restrict__ outb)
{
  __shared__ float a1[4], a2[4];
  int row = blockIdx.x, t = threadIdx.x;
  int hh = t >> 4;                     // 4 cols per thread, 64 cols per head
  int bh = (row >> 11) * NH_ + hh;
  int q = row & (S_ - 1);
  float2 a = ml[(size_t)bh * S_ + q];
  float2 c = ml[(size_t)(32 + bh) * S_ + q];
  float m = fmaxf(a.x, c.x);
  float w0 = exp2f(a.x - m), w1 = exp2f(c.x - m);
  float inv0 = 1.0f / (a.y * w0 + c.y * w1);
  float4 v  = ((const float4*)(x  + (size_t)row * H_))[t];
  float4 u0 = ((const float4*)(o0 + (size_t)row * H_))[t];
  float4 u1 = ((const float4*)(o1 + (size_t)row * H_))[t];
  v.x += (u0.x * w0 + u1.x * w1) * inv0;
  v.y += (u0.y * w0 + u1.y * w1) * inv0;
  v.z += (u0.z * w0 + u1.z * w1) * inv0;
  v.w += (u0.w * w0 + u1.w * w1) * inv0;
  float s1 = v.x + v.y + v.z + v.w;
  float s2 = v.x * v.x + v.y * v.y + v.z * v.z + v.w * v.w;
  #pragma unroll
  for (int d = 32; d; d >>= 1) { s1 += __shfl_xor(s1, d); s2 += __shfl_xor(s2, d); }
  if ((t & 63) == 0) { a1[t >> 6] = s1; a2[t >> 6] = s2; }
  __syncthreads();
  s1 = a1[0] + a1[1] + a1[2] + a1[3];
  s2 = a2[0] + a2[1] + a2[2] + a2[3];
  float mean = s1 * (1.0f / H_);
  float var = s2 * (1.0f / H_) - mean * mean;
  float inv = rsqrtf(var + 1e-5f);
  float4 gv = ((const float4*)g)[t];
  float4 bv = ((const float4*)bb)[t];
  float4 o;
  o.x = (v.x - mean) * inv * gv.x + bv.x;
  o.y = (v.y - mean) * inv * gv.y + bv.y;
  o.z = (v.z - mean) * inv * gv.z + bv.z;
  o.w = (v.w - mean) * inv * gv.w + bv.w;
  if (outf) ((float4*)(outf + (size_t)row * H_))[t] = o;   // POST-LN residual
  if (outb) {
    ushort4 ob; ob.x = f2b(o.x); ob.y = f2b(o.y); ob.z = f2b(o.z); ob.w = f2b(o.w);
    ((ushort4*)(outb + (size_t)row * H_))[t] = ob;
  }
}

// -------- fused (x[+y][+y2]) LayerNorm (POST-LN: outf = LN out) ---------------
__global__ __launch_bounds__(256) void add_ln(
    const float* __restrict__ x, const float* __restrict__ y,
    const float* __restrict__ y2,
    const float* __restrict__ g, const float* __restrict__ bb,
    float* __restrict__ outf, unsigned short* __restrict__ outb)
{
  __shared__ float a1[4], a2[4];
  int row = blockIdx.x, t = threadIdx.x;
  float4 v = ((const float4*)(x + (size_t)row * H_))[t];
  if (y) {
    float4 u = ((const float4*)(y + (size_t)row * H_))[t];
    v.x += u.x; v.y += u.y; v.z += u.z; v.w += u.w;
  }
  if (y2) {
    float4 u = ((const float4*)(y2 + (size_t)row * H_))[t];
    v.x += u.x; v.y += u.y; v.z += u.z; v.w += u.w;
  }
  float s1 = v.x + v.y + v.z + v.w;
  float s2 = v.x * v.x + v.y * v.y + v.z * v.z + v.w * v.w;
  #pragma unroll
  for (int d = 32; d; d >>= 1) { s1 += __shfl_xor(s1, d); s2 += __shfl_xor(s2, d); }
  if ((t & 63) == 0) { a1[t >> 6] = s1; a2[t >> 6] = s2; }
  __syncthreads();
  s1 = a1[0] + a1[1] + a1[2] + a1[3];
  s2 = a2[0] + a2[1] + a2[2] + a2[3];
  float mean = s1 * (1.0f / H_);
  float var = s2 * (1.0f / H_) - mean * mean;
  float inv = rsqrtf(var + 1e-5f);
  float4 gv = ((const float4*)g)[t];
  float4 bv = ((const float4*)bb)[t];
  float4 o;
  o.x = (v.x - mean) * inv * gv.x + bv.x;
  o.y = (v.y - mean) * inv * gv.y + bv.y;
  o.z = (v.z - mean) * inv * gv.z + bv.z;
  o.w = (v.w - mean) * inv * gv.w + bv.w;
  if (outf) ((float4*)(outf + (size_t)row * H_))[t] = o;   // POST-LN residual
  if (outb) {
    ushort4 ob; ob.x = f2b(o.x); ob.y = f2b(o.y); ob.z = f2b(o.z); ob.w = f2b(o.w);
    ((ushort4*)(outb + (size_t)row * H_))[t] = ob;
  }
}

// ------------------------------- launcher -------------------------------------
extern "C" void kernel_launch(void* const* d_in, const int* in_sizes, int n_in,
                              void* d_out, int out_size, void* d_ws, size_t ws_size,
                              hipStream_t stream) {
  const int*   ids  = (const int*)d_in[0];
  const float* mask = (const float*)d_in[1];
  const float* tok  = (const float*)d_in[2];
  const float* pos  = (const float*)d_in[3];
  const float* Wq   = (const float*)d_in[4];
  const float* bq   = (const float*)d_in[5];
  const float* Wk   = (const float*)d_in[6];
  const float* bk   = (const float*)d_in[7];
  const float* Wv   = (const float*)d_in[8];
  const float* bv   = (const float*)d_in[9];
  const float* Wi   = (const float*)d_in[10];
  const float* bi   = (const float*)d_in[11];
  const float* Wo   = (const float*)d_in[12];
  const float* bo   = (const float*)d_in[13];
  const float* ln1g = (const float*)d_in[14];
  const float* ln1b = (const float*)d_in[15];
  const float* ln2g = (const float*)d_in[16];
  const float* ln2b = (const float*)d_in[17];
  const float* lnfg = (const float*)d_in[18];
  const float* lnfb = (const float*)d_in[19];
  const float* Wlm  = (const float*)d_in[20];
  float* out = (float*)d_out;

  char* w = (char*)d_ws;
  size_t off = 0;
  auto alloc = [&](size_t bytes) { void* p = w + off; off = (off + bytes + 255) & ~(size_t)255; return p; };
  float* h     = (float*)alloc((size_t)M_ * H_ * 4);
  unsigned short* qkvb  = (unsigned short*)alloc((size_t)M_ * QS_ * 2);
  unsigned short* vtb   = (unsigned short*)alloc((size_t)B_ * NH_ * DH_ * S_ * 2);
  unsigned short* xbf   = (unsigned short*)alloc((size_t)M_ * H_ * 2);
  unsigned short* midbf = (unsigned short*)alloc((size_t)M_ * I_ * 2);
  float* bqkv  = (float*)alloc((size_t)L_ * QS_ * 4);
  float* opart = (float*)alloc((size_t)NSP_ * M_ * H_ * 4);  // flash/MLP2 partials
  float2* mlbuf = (float2*)alloc((size_t)NSP_ * 32 * S_ * 8);

  size_t wqkv_b = (size_t)L_ * 3 * H_ * H_ * 2;
  size_t wi_bb  = (size_t)L_ * I_ * H_ * 2;
  size_t wo_bb  = (size_t)L_ * H_ * I_ * 2;
  size_t wlm_bb = (size_t)V_ * H_ * 2;
  bool big = (ws_size - off) >= (wqkv_b + wi_bb + wo_bb + wlm_bb + 4 * 256);

  unsigned short *wqkv, *wi_a, *wo_a, *wlm_a, *wbuf = nullptr;
  if (big) {
    wqkv  = (unsigned short*)alloc(wqkv_b);
    wi_a  = (unsigned short*)alloc(wi_bb);
    wo_a  = (unsigned short*)alloc(wo_bb);
    wlm_a = (unsigned short*)alloc(wlm_bb);
    qkvcat_all<<<dim3((unsigned)((size_t)L_ * 3 * H_ * H_ / 1024)), 256, 0, stream>>>(Wq, Wk, Wv, wqkv);
    wcvt<<<dim3((unsigned)((size_t)L_ * I_ * H_ / 1024)), 256, 0, stream>>>(Wi, wi_a);
    wcvt<<<dim3((unsigned)((size_t)L_ * H_ * I_ / 1024)), 256, 0, stream>>>(Wo, wo_a);
    wcvt<<<dim3((unsigned)((size_t)V_ * H_ / 1024)), 256, 0, stream>>>(Wlm, wlm_a);
  } else {
    wbuf = (unsigned short*)alloc((size_t)V_ * H_ * 2);
  }

  bcat<<<dim3(L_ * QS_ / 256), 256, 0, stream>>>(bq, bk, bv, bqkv);
  embed_kernel<<<dim3(M_), 256, 0, stream>>>(ids, tok, pos, h, xbf);

  for (int l = 0; l < L_; ++l) {
    const unsigned short* wq_l;
    if (big) wq_l = wqkv + (size_t)l * 3 * H_ * H_;
    else {
      qkvcat<<<dim3(3 * H_ * H_ / 1024), 256, 0, stream>>>(
          Wq + (size_t)l * H_ * H_, Wk + (size_t)l * H_ * H_, Wv + (size_t)l * H_ * H_, wbuf);
      wq_l = wbuf;
    }
    // fused QKV GEMM: Q/K -> qkvb (bf16, stride QS_), V -> vtb transposed
    gemm_bt<3><<<dim3(M_ / 128, QS_ / 128, 1), 256, 0, stream>>>(
        xbf, wq_l, bqkv + (size_t)l * QS_, nullptr, qkvb, vtb, M_, QS_, H_, H_);

    flash_mfma<<<dim3(B_ * NH_ * S_ / 128 * NSP_), 512, 0, stream>>>(
        qkvb, qkvb + H_, vtb, mask, opart, mlbuf);

    // h = LN(h + merged_ctx); xbf = bf16(h)
    add_ln_mrg<<<dim3(M_), 256, 0, stream>>>(
        h, opart, opart + (size_t)M_ * H_, mlbuf,
        ln1g + l * H_, ln1b + l * H_, h, xbf);

    const unsigned short* wi_l;
    if (big) wi_l = wi_a + (size_t)l * I_ * H_;
    else {
      wcvt<<<dim3(I_ * H_ / 1024), 256, 0, stream>>>(Wi + (size_t)l * I_ * H_, wbuf);
      wi_l = wbuf;
    }
    // MLP1 on 128x128 gemm_bt: 1024 blocks (vs 256 with gemm256) -> 4+ blocks/CU
    gemm_bt<1><<<dim3(M_ / 128, I_ / 128, 1), 256, 0, stream>>>(
        xbf, wi_l, bi + l * I_, nullptr, midbf, nullptr, M_, I_, H_, H_);

    const unsigned short* wo_l;
    if (big) wo_l = wo_a + (size_t)l * H_ * I_;
    else {
      wcvt<<<dim3(H_ * I_ / 1024), 256, 0, stream>>>(Wo + (size_t)l * H_ * I_, wbuf);
      wo_l = wbuf;
    }
    // MLP2 split-K x2: z=0 half writes opart[0] (+bias), z=1 half writes opart[1]
    gemm_bt<0><<<dim3(M_ / 128, H_ / 128, 2), 256, 0, stream>>>(
        midbf, wo_l, bo + l * H_, opart, nullptr, nullptr, M_, H_, I_, I_ / 2);

    // h = LN(h + p0 + p1); xbf = bf16(h)
    add_ln<<<dim3(M_), 256, 0, stream>>>(
        h, opart, opart + (size_t)M_ * H_,
        ln2g + l * H_, ln2b + l * H_, h, xbf);
  }

  add_ln<<<dim3(M_), 256, 0, stream>>>(h, nullptr, nullptr, lnfg, lnfb, nullptr, xbf);
  const unsigned short* wlm_l;
  if (big) wlm_l = wlm_a;
  else {
    wcvt<<<dim3(V_ * H_ / 1024), 256, 0, stream>>>(Wlm, wbuf);
    wlm_l = wbuf;
  }
  gemm256<0><<<dim3((M_ / 256) * (V_ / 256)), 512, 0, stream>>>(
      xbf, wlm_l, nullptr, out, nullptr, M_, V_, H_);
}

// Round 20
// 2853.250 us; speedup vs baseline: 1.0334x; 1.0334x over previous
//
#include <hip/hip_runtime.h>
#include <hip/hip_bf16.h>

#define V_ 32000
#define H_ 1024
#define NH_ 16
#define I_ 4096
#define L_ 8
#define B_ 2
#define S_ 2048
#define DH_ 64
#define M_ 4096   // B_*S_
#define QS_ 3072  // fused QKV row stride
#define NSP_ 2    // flash split-KV factor

typedef __attribute__((ext_vector_type(4))) float f32x4;
typedef __attribute__((ext_vector_type(8))) short s16x8;

#define BARRIER() do { asm volatile("" ::: "memory"); __builtin_amdgcn_s_barrier(); asm volatile("" ::: "memory"); } while (0)
#define SCHEDB()  __builtin_amdgcn_sched_barrier(0)

__device__ __forceinline__ unsigned short f2b(float f) {
  union { float f; unsigned u; } x; x.f = f;
  return (unsigned short)((x.u + 0x7FFFu + ((x.u >> 16) & 1u)) >> 16);
}

__device__ __forceinline__ void gl_lds16(const unsigned short* g, unsigned short* l) {
  __builtin_amdgcn_global_load_lds(
      (__attribute__((address_space(1))) const void*)g,
      (__attribute__((address_space(3))) void*)l, 16, 0, 0);
}

// ---------------- weight f32 -> bf16 flat convert ------------------------------
__global__ __launch_bounds__(256) void wcvt(const float* __restrict__ src,
                                            unsigned short* __restrict__ dst) {
  size_t i = ((size_t)blockIdx.x * 256 + threadIdx.x) * 4;
  float4 v = *(const float4*)(src + i);
  ushort4 b;
  b.x = f2b(v.x); b.y = f2b(v.y); b.z = f2b(v.z); b.w = f2b(v.w);
  *(ushort4*)(dst + i) = b;
}

// concat per-layer Wq|Wk|Wv (each [H][H]) -> dst [l][3H][H] bf16 (all layers)
__global__ __launch_bounds__(256) void qkvcat_all(const float* __restrict__ q,
                                                  const float* __restrict__ k,
                                                  const float* __restrict__ v,
                                                  unsigned short* __restrict__ dst) {
  size_t i = ((size_t)blockIdx.x * 256 + threadIdx.x) * 4;
  size_t l = i / (3u * H_ * H_);
  size_t r = i - l * (3u * H_ * H_);
  const float* s; size_t off;
  if (r < (size_t)H_ * H_)          { s = q; off = l * H_ * H_ + r; }
  else if (r < 2u * H_ * H_)        { s = k; off = l * H_ * H_ + r - (size_t)H_ * H_; }
  else                              { s = v; off = l * H_ * H_ + r - 2u * H_ * H_; }
  float4 vv = *(const float4*)(s + off);
  ushort4 b;
  b.x = f2b(vv.x); b.y = f2b(vv.y); b.z = f2b(vv.z); b.w = f2b(vv.w);
  *(ushort4*)(dst + i) = b;
}

// concat per-layer Wq|Wk|Wv for ONE layer -> dst [3H][H] bf16 (fallback path)
__global__ __launch_bounds__(256) void qkvcat(const float* __restrict__ q,
                                              const float* __restrict__ k,
                                              const float* __restrict__ v,
                                              unsigned short* __restrict__ dst) {
  int i = (blockIdx.x * 256 + threadIdx.x) * 4;
  const float* s; int off;
  if (i < H_ * H_)          { s = q; off = i; }
  else if (i < 2 * H_ * H_) { s = k; off = i - H_ * H_; }
  else                      { s = v; off = i - 2 * H_ * H_; }
  float4 vv = *(const float4*)(s + off);
  ushort4 b;
  b.x = f2b(vv.x); b.y = f2b(vv.y); b.z = f2b(vv.z); b.w = f2b(vv.w);
  *(ushort4*)(dst + i) = b;
}

// concat biases bq|bk|bv per layer -> [L][3H] f32
__global__ __launch_bounds__(256) void bcat(const float* __restrict__ bq,
                                            const float* __restrict__ bk,
                                            const float* __restrict__ bv,
                                            float* __restrict__ dst) {
  int i = blockIdx.x * 256 + threadIdx.x;       // L_*3*H_ total
  int l = i / (3 * H_), r = i - l * 3 * H_;
  int p = r >> 10, c = r & (H_ - 1);
  const float* s = (p == 0) ? bq : ((p == 1) ? bk : bv);
  dst[i] = s[l * H_ + c];
}

// ---------------- embedding: h = tok[ids] + pos, also bf16 copy ----------------
__global__ __launch_bounds__(256) void embed_kernel(
    const int* __restrict__ ids, const float* __restrict__ tok,
    const float* __restrict__ pos, float* __restrict__ h,
    unsigned short* __restrict__ xbf)
{
  int row = blockIdx.x;
  int c4 = threadIdx.x;
  int id = ids[row];
  int s = row & (S_ - 1);
  float4 tv = ((const float4*)(tok + (size_t)id * H_))[c4];
  float4 pv = ((const float4*)(pos + (size_t)s * H_))[c4];
  float4 v; v.x = tv.x + pv.x; v.y = tv.y + pv.y; v.z = tv.z + pv.z; v.w = tv.w + pv.w;
  ((float4*)(h + (size_t)row * H_))[c4] = v;
  ushort4 b; b.x = f2b(v.x); b.y = f2b(v.y); b.z = f2b(v.z); b.w = f2b(v.w);
  ((ushort4*)(xbf + (size_t)row * H_))[c4] = b;
}

// ---------------- 128x128 GEMM v2: dbuf, 1 barrier/K-step, chunk-XOR swizzle --
// EPI 0: f32 out + bias.  EPI 1: gelu(x+bias) -> bf16.  EPI 2: bias -> bf16.
// EPI 3: QKV fused: Q/K cols -> bf16 at stride N; V cols -> transposed into vt.
template<int EPI>
__global__ __launch_bounds__(256) void gemm_bt(
    const unsigned short* __restrict__ A, const unsigned short* __restrict__ Wb,
    const float* __restrict__ bias, float* __restrict__ outf,
    unsigned short* __restrict__ outb, unsigned short* __restrict__ vt,
    int M, int N, int K, int ksz)
{
  __shared__ unsigned short As[2][128][32];
  __shared__ unsigned short Bs[2][128][32];
  int t = threadIdx.x;
  int lane = t & 63, wid = t >> 6;
  int m0 = blockIdx.x * 128, n0 = blockIdx.y * 128;
  int z = blockIdx.z;
  int koff = z * ksz;
  const float* bz = (z == 0) ? bias : nullptr;
  if (EPI == 0) outf += (size_t)z * M * N;
  int wm = (wid >> 1) * 64, wn = (wid & 1) * 64;
  int fr = lane & 15, hi = lane >> 4;
  int lrow = lane >> 2;
  int lcolsw = (((lane & 3) ^ (lrow & 3)) * 8);  // inverse-swizzled source col
  int ke = ((hi ^ (fr & 3)) * 8);                // swizzled read col (elems)

  f32x4 acc[4][4] = {};

  const unsigned short* Abase = A  + (size_t)(m0 + wid * 32 + lrow) * K + lcolsw;
  const unsigned short* Bbase = Wb + (size_t)(n0 + wid * 32 + lrow) * K + lcolsw;

  auto stage = [&](int s, int k0) {
    gl_lds16(Abase + k0,                  &As[s][wid * 32][0]);
    gl_lds16(Abase + k0 + (size_t)16 * K, &As[s][wid * 32 + 16][0]);
    gl_lds16(Bbase + k0,                  &Bs[s][wid * 32][0]);
    gl_lds16(Bbase + k0 + (size_t)16 * K, &Bs[s][wid * 32 + 16][0]);
  };

  stage(0, koff);

  int cur = 0;
  for (int k0 = koff; k0 < koff + ksz; k0 += 32) {
    asm volatile("s_waitcnt vmcnt(0)" ::: "memory");   // tile cur landed
    BARRIER();
    if (k0 + 32 < koff + ksz) stage(cur ^ 1, k0 + 32); // full K-step of lead time
    SCHEDB();
    s16x8 af[4], bfr[4];
    #pragma unroll
    for (int i = 0; i < 4; ++i) af[i]  = *(const s16x8*)(&As[cur][wm + i * 16 + fr][ke]);
    #pragma unroll
    for (int j = 0; j < 4; ++j) bfr[j] = *(const s16x8*)(&Bs[cur][wn + j * 16 + fr][ke]);
    #pragma unroll
    for (int i = 0; i < 4; ++i)
      #pragma unroll
      for (int j = 0; j < 4; ++j)
        acc[i][j] = __builtin_amdgcn_mfma_f32_16x16x32_bf16(af[i], bfr[j], acc[i][j], 0, 0, 0);
    cur ^= 1;
  }

  int fq = lane >> 4;
  if (EPI == 3) {
    #pragma unroll
    for (int i = 0; i < 4; ++i) {
      #pragma unroll
      for (int j = 0; j < 4; ++j) {
        int col = n0 + wn + j * 16 + fr;
        int row0_ = m0 + wm + i * 16 + fq * 4;
        float bcol = bz ? bz[col] : 0.f;
        if (col < 2 * H_) {
          #pragma unroll
          for (int r = 0; r < 4; ++r)
            outb[(size_t)(row0_ + r) * N + col] = f2b(acc[i][j][r] + bcol);
        } else {
          int d = col - 2 * H_;
          int bh = (row0_ >> 11) * NH_ + (d >> 6);
          int s0 = row0_ & (S_ - 1);
          ushort4 pk;
          pk.x = f2b(acc[i][j][0] + bcol);
          pk.y = f2b(acc[i][j][1] + bcol);
          pk.z = f2b(acc[i][j][2] + bcol);
          pk.w = f2b(acc[i][j][3] + bcol);
          *(ushort4*)(vt + ((size_t)bh * DH_ + (d & 63)) * S_ + s0) = pk;
        }
      }
    }
    return;
  }
  #pragma unroll
  for (int i = 0; i < 4; ++i) {
    #pragma unroll
    for (int j = 0; j < 4; ++j) {
      #pragma unroll
      for (int r = 0; r < 4; ++r) {
        int row = m0 + wm + i * 16 + fq * 4 + r;
        int col = n0 + wn + j * 16 + fr;
        float v = acc[i][j][r] + (bz ? bz[col] : 0.f);
        if (EPI == 0) {
          outf[(size_t)row * N + col] = v;
        } else if (EPI == 1) {
          float ge = 0.5f * v * (1.0f + erff(v * 0.70710678118f));
          outb[(size_t)row * N + col] = f2b(ge);
        } else {
          outb[(size_t)row * N + col] = f2b(v);
        }
      }
    }
  }
}

// ---------------- 256x256 GEMM (r8-proven config: distributed staging) --------
template<int EPI>
__global__ __launch_bounds__(512, 2) void gemm256(
    const unsigned short* __restrict__ A, const unsigned short* __restrict__ Wb,
    const float* __restrict__ bias, float* __restrict__ outf,
    unsigned short* __restrict__ outb, int M, int N, int K)
{
  __shared__ unsigned short ASm[2][16384];   // [slot][256 rows x 64 k]
  __shared__ unsigned short BSm[2][16384];

  const int t = threadIdx.x;
  const int lane = t & 63, wid = t >> 6;
  const int wm = wid >> 2, wn = wid & 3;          // 2 x 4 wave grid
  const int fr = lane & 15, hi = lane >> 4;

  const int Nt = N >> 8;
  const int nwg = gridDim.x;
  const int cpx = nwg >> 3;
  int bid = (int)blockIdx.x;
  int swz = (bid & 7) * cpx + (bid >> 3);
  int band = swz / (4 * Nt);
  int rem = swz - band * (4 * Nt);
  const int m0 = (band * 4 + (rem & 3)) << 8;
  const int n0 = (rem >> 2) << 8;

  const int NT = K >> 6;

  const int srow = lane >> 3;
  const int scol = ((lane & 7) ^ srow) << 3;
  const int ch0 = wid * 2;

  const int axorb = (fr & 7) << 4;
  const int koe0 = ((hi * 16) ^ axorb) >> 1;
  const int koe1 = (((hi * 16) | 64) ^ axorb) >> 1;

  f32x4 acc[8][4] = {};

  auto stage_half = [&](int slot, int h, int k0) {
    if (h < 2) {
      const unsigned short* src =
          A + (size_t)(m0 + h * 128 + ch0 * 8 + srow) * K + k0 + scol;
      unsigned short* dst = &ASm[slot][(h * 128 + ch0 * 8) * 64];
      gl_lds16(src, dst);
      gl_lds16(src + (size_t)8 * K, dst + 8 * 64);
    } else {
      const unsigned short* src =
          Wb + (size_t)(n0 + (h - 2) * 128 + ch0 * 8 + srow) * K + k0 + scol;
      unsigned short* dst = &BSm[slot][((h - 2) * 128 + ch0 * 8) * 64];
      gl_lds16(src, dst);
      gl_lds16(src + (size_t)8 * K, dst + 8 * 64);
    }
  };

  // prologue: tile0 -> slot0 (B first for HBM cover, then A)
  stage_half(0, 2, 0); stage_half(0, 3, 0); stage_half(0, 0, 0); stage_half(0, 1, 0);

  s16x8 af0[4][2], af1[4][2], bfv[4][2];

  for (int T = 0; T < NT; ++T) {
    const int s = T & 1;
    const int k1 = (T + 1) << 6;
    const bool more = (T + 1 < NT);

    asm volatile("s_waitcnt vmcnt(0)" ::: "memory");   // tile T fully landed
    BARRIER();

    const unsigned short* As_ = ASm[s];
    const unsigned short* Bs_ = BSm[s];

    // ---- R0: af0 (m0-3) + all bfv ; stage B-half0(T+1) ----
    #pragma unroll
    for (int mi = 0; mi < 4; ++mi) {
      const unsigned short* p = As_ + (wm * 128 + mi * 16 + fr) * 64;
      af0[mi][0] = *(const s16x8*)(p + koe0);
      af0[mi][1] = *(const s16x8*)(p + koe1);
    }
    #pragma unroll
    for (int nj = 0; nj < 4; ++nj) {
      const unsigned short* p = Bs_ + (wn * 64 + nj * 16 + fr) * 64;
      bfv[nj][0] = *(const s16x8*)(p + koe0);
      bfv[nj][1] = *(const s16x8*)(p + koe1);
    }
    if (more) stage_half(s ^ 1, 2, k1);
    SCHEDB();
    __builtin_amdgcn_s_setprio(1);
    #pragma unroll
    for (int mi = 0; mi < 4; ++mi)
      #pragma unroll
      for (int nj = 0; nj < 2; ++nj) {
        acc[mi][nj] = __builtin_amdgcn_mfma_f32_16x16x32_bf16(af0[mi][0], bfv[nj][0], acc[mi][nj], 0, 0, 0);
        acc[mi][nj] = __builtin_amdgcn_mfma_f32_16x16x32_bf16(af0[mi][1], bfv[nj][1], acc[mi][nj], 0, 0, 0);
      }
    __builtin_amdgcn_s_setprio(0);
    SCHEDB();

    // ---- R2: af1 (m4-7) ; stage B-half1(T+1) ----
    #pragma unroll
    for (int mi = 0; mi < 4; ++mi) {
      const unsigned short* p = As_ + (wm * 128 + (mi + 4) * 16 + fr) * 64;
      af1[mi][0] = *(const s16x8*)(p + koe0);
      af1[mi][1] = *(const s16x8*)(p + koe1);
    }
    if (more) stage_half(s ^ 1, 3, k1);
    SCHEDB();
    __builtin_amdgcn_s_setprio(1);
    #pragma unroll
    for (int mi = 0; mi < 4; ++mi)
      #pragma unroll
      for (int nj = 2; nj < 4; ++nj) {
        acc[mi][nj] = __builtin_amdgcn_mfma_f32_16x16x32_bf16(af0[mi][0], bfv[nj][0], acc[mi][nj], 0, 0, 0);
        acc[mi][nj] = __builtin_amdgcn_mfma_f32_16x16x32_bf16(af0[mi][1], bfv[nj][1], acc[mi][nj], 0, 0, 0);
      }
    __builtin_amdgcn_s_setprio(0);
    SCHEDB();

    // ---- stage A-half0(T+1) ; G2: m4-7 x n2-3 ----
    if (more) stage_half(s ^ 1, 0, k1);
    SCHEDB();
    __builtin_amdgcn_s_setprio(1);
    #pragma unroll
    for (int mi = 0; mi < 4; ++mi)
      #pragma unroll
      for (int nj = 2; nj < 4; ++nj) {
        acc[mi + 4][nj] = __builtin_amdgcn_mfma_f32_16x16x32_bf16(af1[mi][0], bfv[nj][0], acc[mi + 4][nj], 0, 0, 0);
        acc[mi + 4][nj] = __builtin_amdgcn_mfma_f32_16x16x32_bf16(af1[mi][1], bfv[nj][1], acc[mi + 4][nj], 0, 0, 0);
      }
    __builtin_amdgcn_s_setprio(0);
    SCHEDB();

    // ---- stage A-half1(T+1) ; G3: m4-7 x n0-1 ----
    if (more) stage_half(s ^ 1, 1, k1);
    SCHEDB();
    __builtin_amdgcn_s_setprio(1);
    #pragma unroll
    for (int mi = 0; mi < 4; ++mi)
      #pragma unroll
      for (int nj = 0; nj < 2; ++nj) {
        acc[mi + 4][nj] = __builtin_amdgcn_mfma_f32_16x16x32_bf16(af1[mi][0], bfv[nj][0], acc[mi + 4][nj], 0, 0, 0);
        acc[mi + 4][nj] = __builtin_amdgcn_mfma_f32_16x16x32_bf16(af1[mi][1], bfv[nj][1], acc[mi + 4][nj], 0, 0, 0);
      }
    __builtin_amdgcn_s_setprio(0);
  }

  #pragma unroll
  for (int mi = 0; mi < 8; ++mi) {
    #pragma unroll
    for (int nj = 0; nj < 4; ++nj) {
      #pragma unroll
      for (int r = 0; r < 4; ++r) {
        int row = m0 + wm * 128 + mi * 16 + hi * 4 + r;
        int col = n0 + wn * 64 + nj * 16 + fr;
        float v = acc[mi][nj][r] + (bias ? bias[col] : 0.f);
        if (EPI == 0) {
          outf[(size_t)row * N + col] = v;
        } else if (EPI == 1) {
          float ge = 0.5f * v * (1.0f + erff(v * 0.70710678118f));
          outb[(size_t)row * N + col] = f2b(ge);
        } else {
          outb[(size_t)row * N + col] = f2b(v);
        }
      }
    }
  }
}

// ---------------- MFMA flash attention v7 (r17/r18 equal-best config) ---------
#define KB_ 64
#define SPL_ 1024
__global__ __launch_bounds__(512, 2) void flash_mfma(
    const unsigned short* __restrict__ qb,  // q slice base (stride QS_)
    const unsigned short* __restrict__ kb,  // k slice base (stride QS_)
    const unsigned short* __restrict__ vtb, // [B*NH][DH][S] bf16
    const float* __restrict__ mask,         // [B][S]
    float* __restrict__ opart,              // [NSP_][M][H] unnormalized
    float2* __restrict__ ml)                // [NSP_][32][S] (m, l)
{
  __shared__ unsigned short K2[2][KB_ * DH_];   // [slot][kv][d] swizzled
  __shared__ unsigned short V2[2][DH_ * KB_];   // [slot][d][kv] swizzled
  __shared__ unsigned short Ps[8][16][72];      // per-wave P [q][kv], padded
  __shared__ float xpose[8][16];                // per-wave q-transpose bounce

  const float LOG2E = 1.4426950408889634f;
  const float SCL = 0.125f * LOG2E;
  int t = threadIdx.x, lane = t & 63, wid = t >> 6;   // wid 0..7
  int blk = blockIdx.x;
  int bh = blk & 31;                    // bh fastest => same head -> same XCD
  int rest = blk >> 5;
  int qt = rest & 15, sp = rest >> 4;   // sp 0..1
  int b = bh >> 4, hh = bh & 15;
  int row0 = b * S_ + qt * 128 + wid * 16;
  int fr = lane & 15, hi = lane >> 4;
  const float* mrow = mask + (size_t)b * S_;
  const int kv0 = sp * SPL_;

  s16x8 qf[2];
  {
    const unsigned short* qrow = qb + (size_t)(row0 + fr) * QS_ + hh * DH_;
    qf[0] = *(const s16x8*)(qrow + hi * 8);
    qf[1] = *(const s16x8*)(qrow + 32 + hi * 8);
  }

  float m_run = -3.0e38f, l_run = 0.f;   // per q=fr (replicated over hi)
  f32x4 octx[4] = {};

  const unsigned short* Kbase = kb + (size_t)b * S_ * QS_ + hh * DH_;
  const unsigned short* Vbase = vtb + (size_t)bh * DH_ * S_;

  int crow = lane >> 3;
  int scol = ((lane & 7) ^ crow) * 8;

  auto stage = [&](int slot, int t0) {
    gl_lds16(Kbase + (size_t)(t0 + wid * 8 + crow) * QS_ + scol, &K2[slot][wid * 512]);
    gl_lds16(Vbase + (size_t)(wid * 8 + crow) * S_ + t0 + scol,  &V2[slot][wid * 512]);
  };

  stage(0, kv0);

  const int swz = (fr & 7) * 8;

  int tt = 0;
  for (int t0 = kv0; t0 < kv0 + SPL_; t0 += KB_, ++tt) {
    int slot = tt & 1;
    __syncthreads();
    if (t0 + KB_ < kv0 + SPL_) stage(slot ^ 1, t0 + KB_);

    // QK^T swapped: sacc[g] = mfma(K rows, Q) -> C[m=kv][n=q]
    f32x4 sacc[4] = {};
    #pragma unroll
    for (int g = 0; g < 4; ++g) {
      #pragma unroll
      for (int i = 0; i < 2; ++i) {
        s16x8 kf = *(const s16x8*)(&K2[slot][(g * 16 + fr) * 64 + ((i * 32 + hi * 8) ^ swz)]);
        sacc[g] = __builtin_amdgcn_mfma_f32_16x16x32_bf16(kf, qf[i], sacc[g], 0, 0, 0);
      }
    }

    // scale + mask in place; track tile max
    float tm = -3.0e38f;
    #pragma unroll
    for (int g = 0; g < 4; ++g) {
      float4 mq = *(const float4*)(mrow + t0 + g * 16 + hi * 4);
      #pragma unroll
      for (int r = 0; r < 4; ++r) {
        float mk = (1.0f - ((const float*)&mq)[r]) * (-10000.0f * LOG2E);
        float v = sacc[g][r] * SCL + mk;
        sacc[g][r] = v;
        tm = fmaxf(tm, v);
      }
    }
    tm = fmaxf(tm, __shfl_xor(tm, 16));
    tm = fmaxf(tm, __shfl_xor(tm, 32));

    if (!__all(tm <= m_run + 8.0f)) {
      float mn = fmaxf(m_run, tm);
      float corr = exp2f(m_run - mn);
      m_run = mn; l_run *= corr;
      xpose[wid][fr] = corr;
      float cr0 = xpose[wid][hi * 4 + 0];
      float cr1 = xpose[wid][hi * 4 + 1];
      float cr2 = xpose[wid][hi * 4 + 2];
      float cr3 = xpose[wid][hi * 4 + 3];
      #pragma unroll
      for (int dg = 0; dg < 4; ++dg) {
        octx[dg][0] *= cr0; octx[dg][1] *= cr1;
        octx[dg][2] *= cr2; octx[dg][3] *= cr3;
      }
    }

    // exp + pack + stream to Ps per group (short live ranges)
    float ps = 0.f;
    #pragma unroll
    for (int g = 0; g < 4; ++g) {
      float p0 = exp2f(sacc[g][0] - m_run);
      float p1 = exp2f(sacc[g][1] - m_run);
      float p2 = exp2f(sacc[g][2] - m_run);
      float p3 = exp2f(sacc[g][3] - m_run);
      ps += (p0 + p1) + (p2 + p3);
      uint2 pk;
      pk.x = (unsigned)f2b(p0) | ((unsigned)f2b(p1) << 16);
      pk.y = (unsigned)f2b(p2) | ((unsigned)f2b(p3) << 16);
      *(uint2*)(&Ps[wid][fr][g * 16 + hi * 4]) = pk;
    }
    ps += __shfl_xor(ps, 16);
    ps += __shfl_xor(ps, 32);
    l_run += ps;

    #pragma unroll
    for (int kc = 0; kc < 2; ++kc) {
      s16x8 pf = *(const s16x8*)(&Ps[wid][fr][kc * 32 + hi * 8]);
      #pragma unroll
      for (int dg = 0; dg < 4; ++dg) {
        s16x8 vf2 = *(const s16x8*)(&V2[slot][(dg * 16 + fr) * 64 + ((kc * 32 + hi * 8) ^ swz)]);
        octx[dg] = __builtin_amdgcn_mfma_f32_16x16x32_bf16(pf, vf2, octx[dg], 0, 0, 0);
      }
    }
  }

  float* ob = opart + (size_t)sp * M_ * H_;
  #pragma unroll
  for (int dg = 0; dg < 4; ++dg) {
    size_t base = (size_t)(row0 + hi * 4) * H_ + hh * DH_ + dg * 16 + fr;
    ob[base]          = octx[dg][0];
    ob[base + H_]     = octx[dg][1];
    ob[base + 2 * H_] = octx[dg][2];
    ob[base + 3 * H_] = octx[dg][3];
  }
  if (hi == 0)
    ml[((size_t)sp * 32 + bh) * S_ + qt * 128 + wid * 16 + fr] =
        make_float2(m_run, l_run);
}

// -------- fused 2-way attn-merge + residual + LayerNorm (POST-LN) -------------
__global__ __launch_bounds__(256) void add_ln_mrg(
    const float* __restrict__ x, const float* __restrict__ o0,
    const float* __restrict__ o1, const float2* __restrict__ ml,
    const float* __restrict__ g, const float* __restrict__ bb,
    float* __restrict__ outf, unsigned short* __restrict__ outb)
{
  __shared__ float a1[4], a2[4];
  int row = blockIdx.x, t = threadIdx.x;
  int hh = t >> 4;                     // 4 cols per thread, 64 cols per head
  int bh = (row >> 11) * NH_ + hh;
  int q = row & (S_ - 1);
  float2 a = ml[(size_t)bh * S_ + q];
  float2 c = ml[(size_t)(32 + bh) * S_ + q];
  float m = fmaxf(a.x, c.x);
  float w0 = exp2f(a.x - m), w1 = exp2f(c.x - m);
  float inv0 = 1.0f / (a.y * w0 + c.y * w1);
  float4 v  = ((const float4*)(x  + (size_t)row * H_))[t];
  float4 u0 = ((const float4*)(o0 + (size_t)row * H_))[t];
  float4 u1 = ((const float4*)(o1 + (size_t)row * H_))[t];
  v.x += (u0.x * w0 + u1.x * w1) * inv0;
  v.y += (u0.y * w0 + u1.y * w1) * inv0;
  v.z += (u0.z * w0 + u1.z * w1) * inv0;
  v.w += (u0.w * w0 + u1.w * w1) * inv0;
  float s1 = v.x + v.y + v.z + v.w;
  float s2 = v.x * v.x + v.y * v.y + v.z * v.z + v.w * v.w;
  #pragma unroll
  for (int d = 32; d; d >>= 1) { s1 += __shfl_xor(s1, d); s2 += __shfl_xor(s2, d); }
  if ((t & 63) == 0) { a1[t >> 6] = s1; a2[t >> 6] = s2; }
  __syncthreads();
  s1 = a1[0] + a1[1] + a1[2] + a1[3];
  s2 = a2[0] + a2[1] + a2[2] + a2[3];
  float mean = s1 * (1.0f / H_);
  float var = s2 * (1.0f / H_) - mean * mean;
  float inv = rsqrtf(var + 1e-5f);
  float4 gv = ((const float4*)g)[t];
  float4 bv = ((const float4*)bb)[t];
  float4 o;
  o.x = (v.x - mean) * inv * gv.x + bv.x;
  o.y = (v.y - mean) * inv * gv.y + bv.y;
  o.z = (v.z - mean) * inv * gv.z + bv.z;
  o.w = (v.w - mean) * inv * gv.w + bv.w;
  if (outf) ((float4*)(outf + (size_t)row * H_))[t] = o;   // POST-LN residual
  if (outb) {
    ushort4 ob; ob.x = f2b(o.x); ob.y = f2b(o.y); ob.z = f2b(o.z); ob.w = f2b(o.w);
    ((ushort4*)(outb + (size_t)row * H_))[t] = ob;
  }
}

// -------- fused (x[+y][+y2]) LayerNorm (POST-LN: outf = LN out) ---------------
__global__ __launch_bounds__(256) void add_ln(
    const float* __restrict__ x, const float* __restrict__ y,
    const float* __restrict__ y2,
    const float* __restrict__ g, const float* __restrict__ bb,
    float* __restrict__ outf, unsigned short* __restrict__ outb)
{
  __shared__ float a1[4], a2[4];
  int row = blockIdx.x, t = threadIdx.x;
  float4 v = ((const float4*)(x + (size_t)row * H_))[t];
  if (y) {
    float4 u = ((const float4*)(y + (size_t)row * H_))[t];
    v.x += u.x; v.y += u.y; v.z += u.z; v.w += u.w;
  }
  if (y2) {
    float4 u = ((const float4*)(y2 + (size_t)row * H_))[t];
    v.x += u.x; v.y += u.y; v.z += u.z; v.w += u.w;
  }
  float s1 = v.x + v.y + v.z + v.w;
  float s2 = v.x * v.x + v.y * v.y + v.z * v.z + v.w * v.w;
  #pragma unroll
  for (int d = 32; d; d >>= 1) { s1 += __shfl_xor(s1, d); s2 += __shfl_xor(s2, d); }
  if ((t & 63) == 0) { a1[t >> 6] = s1; a2[t >> 6] = s2; }
  __syncthreads();
  s1 = a1[0] + a1[1] + a1[2] + a1[3];
  s2 = a2[0] + a2[1] + a2[2] + a2[3];
  float mean = s1 * (1.0f / H_);
  float var = s2 * (1.0f / H_) - mean * mean;
  float inv = rsqrtf(var + 1e-5f);
  float4 gv = ((const float4*)g)[t];
  float4 bv = ((const float4*)bb)[t];
  float4 o;
  o.x = (v.x - mean) * inv * gv.x + bv.x;
  o.y = (v.y - mean) * inv * gv.y + bv.y;
  o.z = (v.z - mean) * inv * gv.z + bv.z;
  o.w = (v.w - mean) * inv * gv.w + bv.w;
  if (outf) ((float4*)(outf + (size_t)row * H_))[t] = o;   // POST-LN residual
  if (outb) {
    ushort4 ob; ob.x = f2b(o.x); ob.y = f2b(o.y); ob.z = f2b(o.z); ob.w = f2b(o.w);
    ((ushort4*)(outb + (size_t)row * H_))[t] = ob;
  }
}

// ------------------------------- launcher -------------------------------------
extern "C" void kernel_launch(void* const* d_in, const int* in_sizes, int n_in,
                              void* d_out, int out_size, void* d_ws, size_t ws_size,
                              hipStream_t stream) {
  const int*   ids  = (const int*)d_in[0];
  const float* mask = (const float*)d_in[1];
  const float* tok  = (const float*)d_in[2];
  const float* pos  = (const float*)d_in[3];
  const float* Wq   = (const float*)d_in[4];
  const float* bq   = (const float*)d_in[5];
  const float* Wk   = (const float*)d_in[6];
  const float* bk   = (const float*)d_in[7];
  const float* Wv   = (const float*)d_in[8];
  const float* bv   = (const float*)d_in[9];
  const float* Wi   = (const float*)d_in[10];
  const float* bi   = (const float*)d_in[11];
  const float* Wo   = (const float*)d_in[12];
  const float* bo   = (const float*)d_in[13];
  const float* ln1g = (const float*)d_in[14];
  const float* ln1b = (const float*)d_in[15];
  const float* ln2g = (const float*)d_in[16];
  const float* ln2b = (const float*)d_in[17];
  const float* lnfg = (const float*)d_in[18];
  const float* lnfb = (const float*)d_in[19];
  const float* Wlm  = (const float*)d_in[20];
  float* out = (float*)d_out;

  char* w = (char*)d_ws;
  size_t off = 0;
  auto alloc = [&](size_t bytes) { void* p = w + off; off = (off + bytes + 255) & ~(size_t)255; return p; };
  float* h     = (float*)alloc((size_t)M_ * H_ * 4);
  unsigned short* qkvb  = (unsigned short*)alloc((size_t)M_ * QS_ * 2);
  unsigned short* vtb   = (unsigned short*)alloc((size_t)B_ * NH_ * DH_ * S_ * 2);
  unsigned short* xbf   = (unsigned short*)alloc((size_t)M_ * H_ * 2);
  unsigned short* midbf = (unsigned short*)alloc((size_t)M_ * I_ * 2);
  float* bqkv  = (float*)alloc((size_t)L_ * QS_ * 4);
  float* opart = (float*)alloc((size_t)NSP_ * M_ * H_ * 4);  // flash/MLP2 partials
  float2* mlbuf = (float2*)alloc((size_t)NSP_ * 32 * S_ * 8);

  size_t wqkv_b = (size_t)L_ * 3 * H_ * H_ * 2;
  size_t wi_bb  = (size_t)L_ * I_ * H_ * 2;
  size_t wo_bb  = (size_t)L_ * H_ * I_ * 2;
  size_t wlm_bb = (size_t)V_ * H_ * 2;
  bool big = (ws_size - off) >= (wqkv_b + wi_bb + wo_bb + wlm_bb + 4 * 256);

  unsigned short *wqkv, *wi_a, *wo_a, *wlm_a, *wbuf = nullptr;
  if (big) {
    wqkv  = (unsigned short*)alloc(wqkv_b);
    wi_a  = (unsigned short*)alloc(wi_bb);
    wo_a  = (unsigned short*)alloc(wo_bb);
    wlm_a = (unsigned short*)alloc(wlm_bb);
    qkvcat_all<<<dim3((unsigned)((size_t)L_ * 3 * H_ * H_ / 1024)), 256, 0, stream>>>(Wq, Wk, Wv, wqkv);
    wcvt<<<dim3((unsigned)((size_t)L_ * I_ * H_ / 1024)), 256, 0, stream>>>(Wi, wi_a);
    wcvt<<<dim3((unsigned)((size_t)L_ * H_ * I_ / 1024)), 256, 0, stream>>>(Wo, wo_a);
    wcvt<<<dim3((unsigned)((size_t)V_ * H_ / 1024)), 256, 0, stream>>>(Wlm, wlm_a);
  } else {
    wbuf = (unsigned short*)alloc((size_t)V_ * H_ * 2);
  }

  bcat<<<dim3(L_ * QS_ / 256), 256, 0, stream>>>(bq, bk, bv, bqkv);
  embed_kernel<<<dim3(M_), 256, 0, stream>>>(ids, tok, pos, h, xbf);

  for (int l = 0; l < L_; ++l) {
    const unsigned short* wq_l;
    if (big) wq_l = wqkv + (size_t)l * 3 * H_ * H_;
    else {
      qkvcat<<<dim3(3 * H_ * H_ / 1024), 256, 0, stream>>>(
          Wq + (size_t)l * H_ * H_, Wk + (size_t)l * H_ * H_, Wv + (size_t)l * H_ * H_, wbuf);
      wq_l = wbuf;
    }
    // fused QKV GEMM: Q/K -> qkvb (bf16, stride QS_), V -> vtb transposed
    gemm_bt<3><<<dim3(M_ / 128, QS_ / 128, 1), 256, 0, stream>>>(
        xbf, wq_l, bqkv + (size_t)l * QS_, nullptr, qkvb, vtb, M_, QS_, H_, H_);

    flash_mfma<<<dim3(B_ * NH_ * S_ / 128 * NSP_), 512, 0, stream>>>(
        qkvb, qkvb + H_, vtb, mask, opart, mlbuf);

    // h = LN(h + merged_ctx); xbf = bf16(h)
    add_ln_mrg<<<dim3(M_), 256, 0, stream>>>(
        h, opart, opart + (size_t)M_ * H_, mlbuf,
        ln1g + l * H_, ln1b + l * H_, h, xbf);

    const unsigned short* wi_l;
    if (big) wi_l = wi_a + (size_t)l * I_ * H_;
    else {
      wcvt<<<dim3(I_ * H_ / 1024), 256, 0, stream>>>(Wi + (size_t)l * I_ * H_, wbuf);
      wi_l = wbuf;
    }
    gemm256<1><<<dim3((M_ / 256) * (I_ / 256)), 512, 0, stream>>>(
        xbf, wi_l, bi + l * I_, nullptr, midbf, M_, I_, H_);

    const unsigned short* wo_l;
    if (big) wo_l = wo_a + (size_t)l * H_ * I_;
    else {
      wcvt<<<dim3(H_ * I_ / 1024), 256, 0, stream>>>(Wo + (size_t)l * H_ * I_, wbuf);
      wo_l = wbuf;
    }
    // MLP2 split-K x2: z=0 half writes opart[0] (+bias), z=1 half writes opart[1]
    gemm_bt<0><<<dim3(M_ / 128, H_ / 128, 2), 256, 0, stream>>>(
        midbf, wo_l, bo + l * H_, opart, nullptr, nullptr, M_, H_, I_, I_ / 2);

    // h = LN(h + p0 + p1); xbf = bf16(h)
    add_ln<<<dim3(M_), 256, 0, stream>>>(
        h, opart, opart + (size_t)M_ * H_,
        ln2g + l * H_, ln2b + l * H_, h, xbf);
  }

  add_ln<<<dim3(M_), 256, 0, stream>>>(h, nullptr, nullptr, lnfg, lnfb, nullptr, xbf);
  const unsigned short* wlm_l;
  if (big) wlm_l = wlm_a;
  else {
    wcvt<<<dim3(V_ * H_ / 1024), 256, 0, stream>>>(Wlm, wbuf);
    wlm_l = wbuf;
  }
  gemm256<0><<<dim3((M_ / 256) * (V_ / 256)), 512, 0, stream>>>(
      xbf, wlm_l, nullptr, out, nullptr, M_, V_, H_);
}

// Round 21
// 2822.030 us; speedup vs baseline: 1.0449x; 1.0111x over previous
//
#include <hip/hip_runtime.h>
#include <hip/hip_bf16.h>

#define V_ 32000
#define H_ 1024
#define NH_ 16
#define I_ 4096
#define L_ 8
#define B_ 2
#define S_ 2048
#define DH_ 64
#define M_ 4096   // B_*S_
#define QS_ 3072  // fused QKV row stride
#define NSP_ 2    // flash split-KV factor

typedef __attribute__((ext_vector_type(4))) float f32x4;
typedef __attribute__((ext_vector_type(8))) short s16x8;

#define BARRIER() do { asm volatile("" ::: "memory"); __builtin_amdgcn_s_barrier(); asm volatile("" ::: "memory"); } while (0)
#define SCHEDB()  __builtin_amdgcn_sched_barrier(0)

__device__ __forceinline__ unsigned short f2b(float f) {
  union { float f; unsigned u; } x; x.f = f;
  return (unsigned short)((x.u + 0x7FFFu + ((x.u >> 16) & 1u)) >> 16);
}
__device__ __forceinline__ float b2f(unsigned short u) {
  union { float f; unsigned u; } x; x.u = ((unsigned)u) << 16; return x.f;
}

__device__ __forceinline__ void gl_lds16(const unsigned short* g, unsigned short* l) {
  __builtin_amdgcn_global_load_lds(
      (__attribute__((address_space(1))) const void*)g,
      (__attribute__((address_space(3))) void*)l, 16, 0, 0);
}

// ---------------- weight f32 -> bf16 flat convert ------------------------------
__global__ __launch_bounds__(256) void wcvt(const float* __restrict__ src,
                                            unsigned short* __restrict__ dst) {
  size_t i = ((size_t)blockIdx.x * 256 + threadIdx.x) * 4;
  float4 v = *(const float4*)(src + i);
  ushort4 b;
  b.x = f2b(v.x); b.y = f2b(v.y); b.z = f2b(v.z); b.w = f2b(v.w);
  *(ushort4*)(dst + i) = b;
}

// concat per-layer Wq|Wk|Wv (each [H][H]) -> dst [l][3H][H] bf16 (all layers)
__global__ __launch_bounds__(256) void qkvcat_all(const float* __restrict__ q,
                                                  const float* __restrict__ k,
                                                  const float* __restrict__ v,
                                                  unsigned short* __restrict__ dst) {
  size_t i = ((size_t)blockIdx.x * 256 + threadIdx.x) * 4;
  size_t l = i / (3u * H_ * H_);
  size_t r = i - l * (3u * H_ * H_);
  const float* s; size_t off;
  if (r < (size_t)H_ * H_)          { s = q; off = l * H_ * H_ + r; }
  else if (r < 2u * H_ * H_)        { s = k; off = l * H_ * H_ + r - (size_t)H_ * H_; }
  else                              { s = v; off = l * H_ * H_ + r - 2u * H_ * H_; }
  float4 vv = *(const float4*)(s + off);
  ushort4 b;
  b.x = f2b(vv.x); b.y = f2b(vv.y); b.z = f2b(vv.z); b.w = f2b(vv.w);
  *(ushort4*)(dst + i) = b;
}

// concat per-layer Wq|Wk|Wv for ONE layer -> dst [3H][H] bf16 (fallback path)
__global__ __launch_bounds__(256) void qkvcat(const float* __restrict__ q,
                                              const float* __restrict__ k,
                                              const float* __restrict__ v,
                                              unsigned short* __restrict__ dst) {
  int i = (blockIdx.x * 256 + threadIdx.x) * 4;
  const float* s; int off;
  if (i < H_ * H_)          { s = q; off = i; }
  else if (i < 2 * H_ * H_) { s = k; off = i - H_ * H_; }
  else                      { s = v; off = i - 2 * H_ * H_; }
  float4 vv = *(const float4*)(s + off);
  ushort4 b;
  b.x = f2b(vv.x); b.y = f2b(vv.y); b.z = f2b(vv.z); b.w = f2b(vv.w);
  *(ushort4*)(dst + i) = b;
}

// concat biases bq|bk|bv per layer -> [L][3H] f32
__global__ __launch_bounds__(256) void bcat(const float* __restrict__ bq,
                                            const float* __restrict__ bk,
                                            const float* __restrict__ bv,
                                            float* __restrict__ dst) {
  int i = blockIdx.x * 256 + threadIdx.x;       // L_*3*H_ total
  int l = i / (3 * H_), r = i - l * 3 * H_;
  int p = r >> 10, c = r & (H_ - 1);
  const float* s = (p == 0) ? bq : ((p == 1) ? bk : bv);
  dst[i] = s[l * H_ + c];
}

// ---------------- embedding: h = tok[ids] + pos, also bf16 copy ----------------
__global__ __launch_bounds__(256) void embed_kernel(
    const int* __restrict__ ids, const float* __restrict__ tok,
    const float* __restrict__ pos, float* __restrict__ h,
    unsigned short* __restrict__ xbf)
{
  int row = blockIdx.x;
  int c4 = threadIdx.x;
  int id = ids[row];
  int s = row & (S_ - 1);
  float4 tv = ((const float4*)(tok + (size_t)id * H_))[c4];
  float4 pv = ((const float4*)(pos + (size_t)s * H_))[c4];
  float4 v; v.x = tv.x + pv.x; v.y = tv.y + pv.y; v.z = tv.z + pv.z; v.w = tv.w + pv.w;
  ((float4*)(h + (size_t)row * H_))[c4] = v;
  ushort4 b; b.x = f2b(v.x); b.y = f2b(v.y); b.z = f2b(v.z); b.w = f2b(v.w);
  ((ushort4*)(xbf + (size_t)row * H_))[c4] = b;
}

// ---------------- 128x128 GEMM v2: dbuf, 1 barrier/K-step, chunk-XOR swizzle --
// EPI 0: f32 out + bias.  EPI 1: gelu(x+bias) -> bf16.  EPI 2: bias -> bf16.
// EPI 3: QKV fused: Q/K cols -> bf16 at stride N; V cols -> transposed into vt.
// EPI 4: bf16 partial at z*M*N offset into outb (bias only z==0).
template<int EPI>
__global__ __launch_bounds__(256) void gemm_bt(
    const unsigned short* __restrict__ A, const unsigned short* __restrict__ Wb,
    const float* __restrict__ bias, float* __restrict__ outf,
    unsigned short* __restrict__ outb, unsigned short* __restrict__ vt,
    int M, int N, int K, int ksz)
{
  __shared__ unsigned short As[2][128][32];
  __shared__ unsigned short Bs[2][128][32];
  int t = threadIdx.x;
  int lane = t & 63, wid = t >> 6;
  int m0 = blockIdx.x * 128, n0 = blockIdx.y * 128;
  int z = blockIdx.z;
  int koff = z * ksz;
  const float* bz = (z == 0) ? bias : nullptr;
  if (EPI == 0) outf += (size_t)z * M * N;
  int wm = (wid >> 1) * 64, wn = (wid & 1) * 64;
  int fr = lane & 15, hi = lane >> 4;
  int lrow = lane >> 2;
  int lcolsw = (((lane & 3) ^ (lrow & 3)) * 8);  // inverse-swizzled source col
  int ke = ((hi ^ (fr & 3)) * 8);                // swizzled read col (elems)

  f32x4 acc[4][4] = {};

  const unsigned short* Abase = A  + (size_t)(m0 + wid * 32 + lrow) * K + lcolsw;
  const unsigned short* Bbase = Wb + (size_t)(n0 + wid * 32 + lrow) * K + lcolsw;

  auto stage = [&](int s, int k0) {
    gl_lds16(Abase + k0,                  &As[s][wid * 32][0]);
    gl_lds16(Abase + k0 + (size_t)16 * K, &As[s][wid * 32 + 16][0]);
    gl_lds16(Bbase + k0,                  &Bs[s][wid * 32][0]);
    gl_lds16(Bbase + k0 + (size_t)16 * K, &Bs[s][wid * 32 + 16][0]);
  };

  stage(0, koff);

  int cur = 0;
  for (int k0 = koff; k0 < koff + ksz; k0 += 32) {
    asm volatile("s_waitcnt vmcnt(0)" ::: "memory");   // tile cur landed
    BARRIER();
    if (k0 + 32 < koff + ksz) stage(cur ^ 1, k0 + 32); // full K-step of lead time
    SCHEDB();
    s16x8 af[4], bfr[4];
    #pragma unroll
    for (int i = 0; i < 4; ++i) af[i]  = *(const s16x8*)(&As[cur][wm + i * 16 + fr][ke]);
    #pragma unroll
    for (int j = 0; j < 4; ++j) bfr[j] = *(const s16x8*)(&Bs[cur][wn + j * 16 + fr][ke]);
    #pragma unroll
    for (int i = 0; i < 4; ++i)
      #pragma unroll
      for (int j = 0; j < 4; ++j)
        acc[i][j] = __builtin_amdgcn_mfma_f32_16x16x32_bf16(af[i], bfr[j], acc[i][j], 0, 0, 0);
    cur ^= 1;
  }

  int fq = lane >> 4;
  if (EPI == 3) {
    #pragma unroll
    for (int i = 0; i < 4; ++i) {
      #pragma unroll
      for (int j = 0; j < 4; ++j) {
        int col = n0 + wn + j * 16 + fr;
        int row0_ = m0 + wm + i * 16 + fq * 4;
        float bcol = bz ? bz[col] : 0.f;
        if (col < 2 * H_) {
          #pragma unroll
          for (int r = 0; r < 4; ++r)
            outb[(size_t)(row0_ + r) * N + col] = f2b(acc[i][j][r] + bcol);
        } else {
          int d = col - 2 * H_;
          int bh = (row0_ >> 11) * NH_ + (d >> 6);
          int s0 = row0_ & (S_ - 1);
          ushort4 pk;
          pk.x = f2b(acc[i][j][0] + bcol);
          pk.y = f2b(acc[i][j][1] + bcol);
          pk.z = f2b(acc[i][j][2] + bcol);
          pk.w = f2b(acc[i][j][3] + bcol);
          *(ushort4*)(vt + ((size_t)bh * DH_ + (d & 63)) * S_ + s0) = pk;
        }
      }
    }
    return;
  }
  #pragma unroll
  for (int i = 0; i < 4; ++i) {
    #pragma unroll
    for (int j = 0; j < 4; ++j) {
      #pragma unroll
      for (int r = 0; r < 4; ++r) {
        int row = m0 + wm + i * 16 + fq * 4 + r;
        int col = n0 + wn + j * 16 + fr;
        float v = acc[i][j][r] + (bz ? bz[col] : 0.f);
        if (EPI == 0) {
          outf[(size_t)row * N + col] = v;
        } else if (EPI == 1) {
          float ge = 0.5f * v * (1.0f + erff(v * 0.70710678118f));
          outb[(size_t)row * N + col] = f2b(ge);
        } else if (EPI == 4) {
          outb[(size_t)z * M * N + (size_t)row * N + col] = f2b(v);
        } else {
          outb[(size_t)row * N + col] = f2b(v);
        }
      }
    }
  }
}

// ---------------- 256x256 GEMM (r8-proven config: distributed staging) --------
template<int EPI>
__global__ __launch_bounds__(512, 2) void gemm256(
    const unsigned short* __restrict__ A, const unsigned short* __restrict__ Wb,
    const float* __restrict__ bias, float* __restrict__ outf,
    unsigned short* __restrict__ outb, int M, int N, int K)
{
  __shared__ unsigned short ASm[2][16384];   // [slot][256 rows x 64 k]
  __shared__ unsigned short BSm[2][16384];

  const int t = threadIdx.x;
  const int lane = t & 63, wid = t >> 6;
  const int wm = wid >> 2, wn = wid & 3;          // 2 x 4 wave grid
  const int fr = lane & 15, hi = lane >> 4;

  const int Nt = N >> 8;
  const int nwg = gridDim.x;
  const int cpx = nwg >> 3;
  int bid = (int)blockIdx.x;
  int swz = (bid & 7) * cpx + (bid >> 3);
  int band = swz / (4 * Nt);
  int rem = swz - band * (4 * Nt);
  const int m0 = (band * 4 + (rem & 3)) << 8;
  const int n0 = (rem >> 2) << 8;

  const int NT = K >> 6;

  const int srow = lane >> 3;
  const int scol = ((lane & 7) ^ srow) << 3;
  const int ch0 = wid * 2;

  const int axorb = (fr & 7) << 4;
  const int koe0 = ((hi * 16) ^ axorb) >> 1;
  const int koe1 = (((hi * 16) | 64) ^ axorb) >> 1;

  f32x4 acc[8][4] = {};

  auto stage_half = [&](int slot, int h, int k0) {
    if (h < 2) {
      const unsigned short* src =
          A + (size_t)(m0 + h * 128 + ch0 * 8 + srow) * K + k0 + scol;
      unsigned short* dst = &ASm[slot][(h * 128 + ch0 * 8) * 64];
      gl_lds16(src, dst);
      gl_lds16(src + (size_t)8 * K, dst + 8 * 64);
    } else {
      const unsigned short* src =
          Wb + (size_t)(n0 + (h - 2) * 128 + ch0 * 8 + srow) * K + k0 + scol;
      unsigned short* dst = &BSm[slot][((h - 2) * 128 + ch0 * 8) * 64];
      gl_lds16(src, dst);
      gl_lds16(src + (size_t)8 * K, dst + 8 * 64);
    }
  };

  // prologue: tile0 -> slot0 (B first for HBM cover, then A)
  stage_half(0, 2, 0); stage_half(0, 3, 0); stage_half(0, 0, 0); stage_half(0, 1, 0);

  s16x8 af0[4][2], af1[4][2], bfv[4][2];

  for (int T = 0; T < NT; ++T) {
    const int s = T & 1;
    const int k1 = (T + 1) << 6;
    const bool more = (T + 1 < NT);

    asm volatile("s_waitcnt vmcnt(0)" ::: "memory");   // tile T fully landed
    BARRIER();

    const unsigned short* As_ = ASm[s];
    const unsigned short* Bs_ = BSm[s];

    // ---- R0: af0 (m0-3) + all bfv ; stage B-half0(T+1) ----
    #pragma unroll
    for (int mi = 0; mi < 4; ++mi) {
      const unsigned short* p = As_ + (wm * 128 + mi * 16 + fr) * 64;
      af0[mi][0] = *(const s16x8*)(p + koe0);
      af0[mi][1] = *(const s16x8*)(p + koe1);
    }
    #pragma unroll
    for (int nj = 0; nj < 4; ++nj) {
      const unsigned short* p = Bs_ + (wn * 64 + nj * 16 + fr) * 64;
      bfv[nj][0] = *(const s16x8*)(p + koe0);
      bfv[nj][1] = *(const s16x8*)(p + koe1);
    }
    if (more) stage_half(s ^ 1, 2, k1);
    SCHEDB();
    __builtin_amdgcn_s_setprio(1);
    #pragma unroll
    for (int mi = 0; mi < 4; ++mi)
      #pragma unroll
      for (int nj = 0; nj < 2; ++nj) {
        acc[mi][nj] = __builtin_amdgcn_mfma_f32_16x16x32_bf16(af0[mi][0], bfv[nj][0], acc[mi][nj], 0, 0, 0);
        acc[mi][nj] = __builtin_amdgcn_mfma_f32_16x16x32_bf16(af0[mi][1], bfv[nj][1], acc[mi][nj], 0, 0, 0);
      }
    __builtin_amdgcn_s_setprio(0);
    SCHEDB();

    // ---- R2: af1 (m4-7) ; stage B-half1(T+1) ----
    #pragma unroll
    for (int mi = 0; mi < 4; ++mi) {
      const unsigned short* p = As_ + (wm * 128 + (mi + 4) * 16 + fr) * 64;
      af1[mi][0] = *(const s16x8*)(p + koe0);
      af1[mi][1] = *(const s16x8*)(p + koe1);
    }
    if (more) stage_half(s ^ 1, 3, k1);
    SCHEDB();
    __builtin_amdgcn_s_setprio(1);
    #pragma unroll
    for (int mi = 0; mi < 4; ++mi)
      #pragma unroll
      for (int nj = 2; nj < 4; ++nj) {
        acc[mi][nj] = __builtin_amdgcn_mfma_f32_16x16x32_bf16(af0[mi][0], bfv[nj][0], acc[mi][nj], 0, 0, 0);
        acc[mi][nj] = __builtin_amdgcn_mfma_f32_16x16x32_bf16(af0[mi][1], bfv[nj][1], acc[mi][nj], 0, 0, 0);
      }
    __builtin_amdgcn_s_setprio(0);
    SCHEDB();

    // ---- stage A-half0(T+1) ; G2: m4-7 x n2-3 ----
    if (more) stage_half(s ^ 1, 0, k1);
    SCHEDB();
    __builtin_amdgcn_s_setprio(1);
    #pragma unroll
    for (int mi = 0; mi < 4; ++mi)
      #pragma unroll
      for (int nj = 2; nj < 4; ++nj) {
        acc[mi + 4][nj] = __builtin_amdgcn_mfma_f32_16x16x32_bf16(af1[mi][0], bfv[nj][0], acc[mi + 4][nj], 0, 0, 0);
        acc[mi + 4][nj] = __builtin_amdgcn_mfma_f32_16x16x32_bf16(af1[mi][1], bfv[nj][1], acc[mi + 4][nj], 0, 0, 0);
      }
    __builtin_amdgcn_s_setprio(0);
    SCHEDB();

    // ---- stage A-half1(T+1) ; G3: m4-7 x n0-1 ----
    if (more) stage_half(s ^ 1, 1, k1);
    SCHEDB();
    __builtin_amdgcn_s_setprio(1);
    #pragma unroll
    for (int mi = 0; mi < 4; ++mi)
      #pragma unroll
      for (int nj = 0; nj < 2; ++nj) {
        acc[mi + 4][nj] = __builtin_amdgcn_mfma_f32_16x16x32_bf16(af1[mi][0], bfv[nj][0], acc[mi + 4][nj], 0, 0, 0);
        acc[mi + 4][nj] = __builtin_amdgcn_mfma_f32_16x16x32_bf16(af1[mi][1], bfv[nj][1], acc[mi + 4][nj], 0, 0, 0);
      }
    __builtin_amdgcn_s_setprio(0);
  }

  #pragma unroll
  for (int mi = 0; mi < 8; ++mi) {
    #pragma unroll
    for (int nj = 0; nj < 4; ++nj) {
      #pragma unroll
      for (int r = 0; r < 4; ++r) {
        int row = m0 + wm * 128 + mi * 16 + hi * 4 + r;
        int col = n0 + wn * 64 + nj * 16 + fr;
        float v = acc[mi][nj][r] + (bias ? bias[col] : 0.f);
        if (EPI == 0) {
          outf[(size_t)row * N + col] = v;
        } else if (EPI == 1) {
          float ge = 0.5f * v * (1.0f + erff(v * 0.70710678118f));
          outb[(size_t)row * N + col] = f2b(ge);
        } else {
          outb[(size_t)row * N + col] = f2b(v);
        }
      }
    }
  }
}

// ---------------- MFMA flash attention v7 (bf16 partials) ---------------------
#define KB_ 64
#define SPL_ 1024
__global__ __launch_bounds__(512, 2) void flash_mfma(
    const unsigned short* __restrict__ qb,  // q slice base (stride QS_)
    const unsigned short* __restrict__ kb,  // k slice base (stride QS_)
    const unsigned short* __restrict__ vtb, // [B*NH][DH][S] bf16
    const float* __restrict__ mask,         // [B][S]
    unsigned short* __restrict__ opart,     // [NSP_][M][H] unnormalized bf16
    float2* __restrict__ ml)                // [NSP_][32][S] (m, l)
{
  __shared__ unsigned short K2[2][KB_ * DH_];   // [slot][kv][d] swizzled
  __shared__ unsigned short V2[2][DH_ * KB_];   // [slot][d][kv] swizzled
  __shared__ unsigned short Ps[8][16][72];      // per-wave P [q][kv], padded
  __shared__ float xpose[8][16];                // per-wave q-transpose bounce

  const float LOG2E = 1.4426950408889634f;
  const float SCL = 0.125f * LOG2E;
  int t = threadIdx.x, lane = t & 63, wid = t >> 6;   // wid 0..7
  int blk = blockIdx.x;
  int bh = blk & 31;                    // bh fastest => same head -> same XCD
  int rest = blk >> 5;
  int qt = rest & 15, sp = rest >> 4;   // sp 0..1
  int b = bh >> 4, hh = bh & 15;
  int row0 = b * S_ + qt * 128 + wid * 16;
  int fr = lane & 15, hi = lane >> 4;
  const float* mrow = mask + (size_t)b * S_;
  const int kv0 = sp * SPL_;

  s16x8 qf[2];
  {
    const unsigned short* qrow = qb + (size_t)(row0 + fr) * QS_ + hh * DH_;
    qf[0] = *(const s16x8*)(qrow + hi * 8);
    qf[1] = *(const s16x8*)(qrow + 32 + hi * 8);
  }

  float m_run = -3.0e38f, l_run = 0.f;   // per q=fr (replicated over hi)
  f32x4 octx[4] = {};

  const unsigned short* Kbase = kb + (size_t)b * S_ * QS_ + hh * DH_;
  const unsigned short* Vbase = vtb + (size_t)bh * DH_ * S_;

  int crow = lane >> 3;
  int scol = ((lane & 7) ^ crow) * 8;

  auto stage = [&](int slot, int t0) {
    gl_lds16(Kbase + (size_t)(t0 + wid * 8 + crow) * QS_ + scol, &K2[slot][wid * 512]);
    gl_lds16(Vbase + (size_t)(wid * 8 + crow) * S_ + t0 + scol,  &V2[slot][wid * 512]);
  };

  stage(0, kv0);

  const int swz = (fr & 7) * 8;

  int tt = 0;
  for (int t0 = kv0; t0 < kv0 + SPL_; t0 += KB_, ++tt) {
    int slot = tt & 1;
    __syncthreads();
    if (t0 + KB_ < kv0 + SPL_) stage(slot ^ 1, t0 + KB_);

    // QK^T swapped: sacc[g] = mfma(K rows, Q) -> C[m=kv][n=q]
    f32x4 sacc[4] = {};
    #pragma unroll
    for (int g = 0; g < 4; ++g) {
      #pragma unroll
      for (int i = 0; i < 2; ++i) {
        s16x8 kf = *(const s16x8*)(&K2[slot][(g * 16 + fr) * 64 + ((i * 32 + hi * 8) ^ swz)]);
        sacc[g] = __builtin_amdgcn_mfma_f32_16x16x32_bf16(kf, qf[i], sacc[g], 0, 0, 0);
      }
    }

    // scale + mask in place; track tile max
    float tm = -3.0e38f;
    #pragma unroll
    for (int g = 0; g < 4; ++g) {
      float4 mq = *(const float4*)(mrow + t0 + g * 16 + hi * 4);
      #pragma unroll
      for (int r = 0; r < 4; ++r) {
        float mk = (1.0f - ((const float*)&mq)[r]) * (-10000.0f * LOG2E);
        float v = sacc[g][r] * SCL + mk;
        sacc[g][r] = v;
        tm = fmaxf(tm, v);
      }
    }
    tm = fmaxf(tm, __shfl_xor(tm, 16));
    tm = fmaxf(tm, __shfl_xor(tm, 32));

    if (!__all(tm <= m_run + 8.0f)) {
      float mn = fmaxf(m_run, tm);
      float corr = exp2f(m_run - mn);
      m_run = mn; l_run *= corr;
      xpose[wid][fr] = corr;
      float cr0 = xpose[wid][hi * 4 + 0];
      float cr1 = xpose[wid][hi * 4 + 1];
      float cr2 = xpose[wid][hi * 4 + 2];
      float cr3 = xpose[wid][hi * 4 + 3];
      #pragma unroll
      for (int dg = 0; dg < 4; ++dg) {
        octx[dg][0] *= cr0; octx[dg][1] *= cr1;
        octx[dg][2] *= cr2; octx[dg][3] *= cr3;
      }
    }

    // exp + pack + stream to Ps per group (short live ranges)
    float ps = 0.f;
    #pragma unroll
    for (int g = 0; g < 4; ++g) {
      float p0 = exp2f(sacc[g][0] - m_run);
      float p1 = exp2f(sacc[g][1] - m_run);
      float p2 = exp2f(sacc[g][2] - m_run);
      float p3 = exp2f(sacc[g][3] - m_run);
      ps += (p0 + p1) + (p2 + p3);
      uint2 pk;
      pk.x = (unsigned)f2b(p0) | ((unsigned)f2b(p1) << 16);
      pk.y = (unsigned)f2b(p2) | ((unsigned)f2b(p3) << 16);
      *(uint2*)(&Ps[wid][fr][g * 16 + hi * 4]) = pk;
    }
    ps += __shfl_xor(ps, 16);
    ps += __shfl_xor(ps, 32);
    l_run += ps;

    #pragma unroll
    for (int kc = 0; kc < 2; ++kc) {
      s16x8 pf = *(const s16x8*)(&Ps[wid][fr][kc * 32 + hi * 8]);
      #pragma unroll
      for (int dg = 0; dg < 4; ++dg) {
        s16x8 vf2 = *(const s16x8*)(&V2[slot][(dg * 16 + fr) * 64 + ((kc * 32 + hi * 8) ^ swz)]);
        octx[dg] = __builtin_amdgcn_mfma_f32_16x16x32_bf16(pf, vf2, octx[dg], 0, 0, 0);
      }
    }
  }

  unsigned short* ob = opart + (size_t)sp * M_ * H_;
  #pragma unroll
  for (int dg = 0; dg < 4; ++dg) {
    size_t base = (size_t)(row0 + hi * 4) * H_ + hh * DH_ + dg * 16 + fr;
    ob[base]              = f2b(octx[dg][0]);
    ob[base + H_]         = f2b(octx[dg][1]);
    ob[base + 2 * H_]     = f2b(octx[dg][2]);
    ob[base + 3 * H_]     = f2b(octx[dg][3]);
  }
  if (hi == 0)
    ml[((size_t)sp * 32 + bh) * S_ + qt * 128 + wid * 16 + fr] =
        make_float2(m_run, l_run);
}

// -------- fused 2-way attn-merge (bf16 partials) + residual + LN (POST-LN) ----
__global__ __launch_bounds__(256) void add_ln_mrg(
    const float* __restrict__ x, const unsigned short* __restrict__ o0,
    const unsigned short* __restrict__ o1, const float2* __restrict__ ml,
    const float* __restrict__ g, const float* __restrict__ bb,
    float* __restrict__ outf, unsigned short* __restrict__ outb)
{
  __shared__ float a1[4], a2[4];
  int row = blockIdx.x, t = threadIdx.x;
  int hh = t >> 4;                     // 4 cols per thread, 64 cols per head
  int bh = (row >> 11) * NH_ + hh;
  int q = row & (S_ - 1);
  float2 a = ml[(size_t)bh * S_ + q];
  float2 c = ml[(size_t)(32 + bh) * S_ + q];
  float m = fmaxf(a.x, c.x);
  float w0 = exp2f(a.x - m), w1 = exp2f(c.x - m);
  float inv0 = 1.0f / (a.y * w0 + c.y * w1);
  float4 v  = ((const float4*)(x  + (size_t)row * H_))[t];
  ushort4 b0 = ((const ushort4*)(o0 + (size_t)row * H_))[t];
  ushort4 b1 = ((const ushort4*)(o1 + (size_t)row * H_))[t];
  v.x += (b2f(b0.x) * w0 + b2f(b1.x) * w1) * inv0;
  v.y += (b2f(b0.y) * w0 + b2f(b1.y) * w1) * inv0;
  v.z += (b2f(b0.z) * w0 + b2f(b1.z) * w1) * inv0;
  v.w += (b2f(b0.w) * w0 + b2f(b1.w) * w1) * inv0;
  float s1 = v.x + v.y + v.z + v.w;
  float s2 = v.x * v.x + v.y * v.y + v.z * v.z + v.w * v.w;
  #pragma unroll
  for (int d = 32; d; d >>= 1) { s1 += __shfl_xor(s1, d); s2 += __shfl_xor(s2, d); }
  if ((t & 63) == 0) { a1[t >> 6] = s1; a2[t >> 6] = s2; }
  __syncthreads();
  s1 = a1[0] + a1[1] + a1[2] + a1[3];
  s2 = a2[0] + a2[1] + a2[2] + a2[3];
  float mean = s1 * (1.0f / H_);
  float var = s2 * (1.0f / H_) - mean * mean;
  float inv = rsqrtf(var + 1e-5f);
  float4 gv = ((const float4*)g)[t];
  float4 bv = ((const float4*)bb)[t];
  float4 o;
  o.x = (v.x - mean) * inv * gv.x + bv.x;
  o.y = (v.y - mean) * inv * gv.y + bv.y;
  o.z = (v.z - mean) * inv * gv.z + bv.z;
  o.w = (v.w - mean) * inv * gv.w + bv.w;
  if (outf) ((float4*)(outf + (size_t)row * H_))[t] = o;   // POST-LN residual
  if (outb) {
    ushort4 ob; ob.x = f2b(o.x); ob.y = f2b(o.y); ob.z = f2b(o.z); ob.w = f2b(o.w);
    ((ushort4*)(outb + (size_t)row * H_))[t] = ob;
  }
}

// -------- fused (x[+y][+y2], y/y2 bf16) LayerNorm (POST-LN) -------------------
__global__ __launch_bounds__(256) void add_ln(
    const float* __restrict__ x, const unsigned short* __restrict__ y,
    const unsigned short* __restrict__ y2,
    const float* __restrict__ g, const float* __restrict__ bb,
    float* __restrict__ outf, unsigned short* __restrict__ outb)
{
  __shared__ float a1[4], a2[4];
  int row = blockIdx.x, t = threadIdx.x;
  float4 v = ((const float4*)(x + (size_t)row * H_))[t];
  if (y) {
    ushort4 u = ((const ushort4*)(y + (size_t)row * H_))[t];
    v.x += b2f(u.x); v.y += b2f(u.y); v.z += b2f(u.z); v.w += b2f(u.w);
  }
  if (y2) {
    ushort4 u = ((const ushort4*)(y2 + (size_t)row * H_))[t];
    v.x += b2f(u.x); v.y += b2f(u.y); v.z += b2f(u.z); v.w += b2f(u.w);
  }
  float s1 = v.x + v.y + v.z + v.w;
  float s2 = v.x * v.x + v.y * v.y + v.z * v.z + v.w * v.w;
  #pragma unroll
  for (int d = 32; d; d >>= 1) { s1 += __shfl_xor(s1, d); s2 += __shfl_xor(s2, d); }
  if ((t & 63) == 0) { a1[t >> 6] = s1; a2[t >> 6] = s2; }
  __syncthreads();
  s1 = a1[0] + a1[1] + a1[2] + a1[3];
  s2 = a2[0] + a2[1] + a2[2] + a2[3];
  float mean = s1 * (1.0f / H_);
  float var = s2 * (1.0f / H_) - mean * mean;
  float inv = rsqrtf(var + 1e-5f);
  float4 gv = ((const float4*)g)[t];
  float4 bv = ((const float4*)bb)[t];
  float4 o;
  o.x = (v.x - mean) * inv * gv.x + bv.x;
  o.y = (v.y - mean) * inv * gv.y + bv.y;
  o.z = (v.z - mean) * inv * gv.z + bv.z;
  o.w = (v.w - mean) * inv * gv.w + bv.w;
  if (outf) ((float4*)(outf + (size_t)row * H_))[t] = o;   // POST-LN residual
  if (outb) {
    ushort4 ob; ob.x = f2b(o.x); ob.y = f2b(o.y); ob.z = f2b(o.z); ob.w = f2b(o.w);
    ((ushort4*)(outb + (size_t)row * H_))[t] = ob;
  }
}

// ------------------------------- launcher -------------------------------------
extern "C" void kernel_launch(void* const* d_in, const int* in_sizes, int n_in,
                              void* d_out, int out_size, void* d_ws, size_t ws_size,
                              hipStream_t stream) {
  const int*   ids  = (const int*)d_in[0];
  const float* mask = (const float*)d_in[1];
  const float* tok  = (const float*)d_in[2];
  const float* pos  = (const float*)d_in[3];
  const float* Wq   = (const float*)d_in[4];
  const float* bq   = (const float*)d_in[5];
  const float* Wk   = (const float*)d_in[6];
  const float* bk   = (const float*)d_in[7];
  const float* Wv   = (const float*)d_in[8];
  const float* bv   = (const float*)d_in[9];
  const float* Wi   = (const float*)d_in[10];
  const float* bi   = (const float*)d_in[11];
  const float* Wo   = (const float*)d_in[12];
  const float* bo   = (const float*)d_in[13];
  const float* ln1g = (const float*)d_in[14];
  const float* ln1b = (const float*)d_in[15];
  const float* ln2g = (const float*)d_in[16];
  const float* ln2b = (const float*)d_in[17];
  const float* lnfg = (const float*)d_in[18];
  const float* lnfb = (const float*)d_in[19];
  const float* Wlm  = (const float*)d_in[20];
  float* out = (float*)d_out;

  char* w = (char*)d_ws;
  size_t off = 0;
  auto alloc = [&](size_t bytes) { void* p = w + off; off = (off + bytes + 255) & ~(size_t)255; return p; };
  float* h     = (float*)alloc((size_t)M_ * H_ * 4);
  unsigned short* qkvb  = (unsigned short*)alloc((size_t)M_ * QS_ * 2);
  unsigned short* vtb   = (unsigned short*)alloc((size_t)B_ * NH_ * DH_ * S_ * 2);
  unsigned short* xbf   = (unsigned short*)alloc((size_t)M_ * H_ * 2);
  unsigned short* midbf = (unsigned short*)alloc((size_t)M_ * I_ * 2);
  float* bqkv  = (float*)alloc((size_t)L_ * QS_ * 4);
  unsigned short* opart = (unsigned short*)alloc((size_t)NSP_ * M_ * H_ * 2);  // bf16 partials
  float2* mlbuf = (float2*)alloc((size_t)NSP_ * 32 * S_ * 8);

  size_t wqkv_b = (size_t)L_ * 3 * H_ * H_ * 2;
  size_t wi_bb  = (size_t)L_ * I_ * H_ * 2;
  size_t wo_bb  = (size_t)L_ * H_ * I_ * 2;
  size_t wlm_bb = (size_t)V_ * H_ * 2;
  bool big = (ws_size - off) >= (wqkv_b + wi_bb + wo_bb + wlm_bb + 4 * 256);

  unsigned short *wqkv, *wi_a, *wo_a, *wlm_a, *wbuf = nullptr;
  if (big) {
    wqkv  = (unsigned short*)alloc(wqkv_b);
    wi_a  = (unsigned short*)alloc(wi_bb);
    wo_a  = (unsigned short*)alloc(wo_bb);
    wlm_a = (unsigned short*)alloc(wlm_bb);
    qkvcat_all<<<dim3((unsigned)((size_t)L_ * 3 * H_ * H_ / 1024)), 256, 0, stream>>>(Wq, Wk, Wv, wqkv);
    wcvt<<<dim3((unsigned)((size_t)L_ * I_ * H_ / 1024)), 256, 0, stream>>>(Wi, wi_a);
    wcvt<<<dim3((unsigned)((size_t)L_ * H_ * I_ / 1024)), 256, 0, stream>>>(Wo, wo_a);
    wcvt<<<dim3((unsigned)((size_t)V_ * H_ / 1024)), 256, 0, stream>>>(Wlm, wlm_a);
  } else {
    wbuf = (unsigned short*)alloc((size_t)V_ * H_ * 2);
  }

  bcat<<<dim3(L_ * QS_ / 256), 256, 0, stream>>>(bq, bk, bv, bqkv);
  embed_kernel<<<dim3(M_), 256, 0, stream>>>(ids, tok, pos, h, xbf);

  for (int l = 0; l < L_; ++l) {
    const unsigned short* wq_l;
    if (big) wq_l = wqkv + (size_t)l * 3 * H_ * H_;
    else {
      qkvcat<<<dim3(3 * H_ * H_ / 1024), 256, 0, stream>>>(
          Wq + (size_t)l * H_ * H_, Wk + (size_t)l * H_ * H_, Wv + (size_t)l * H_ * H_, wbuf);
      wq_l = wbuf;
    }
    // fused QKV GEMM: Q/K -> qkvb (bf16, stride QS_), V -> vtb transposed
    gemm_bt<3><<<dim3(M_ / 128, QS_ / 128, 1), 256, 0, stream>>>(
        xbf, wq_l, bqkv + (size_t)l * QS_, nullptr, qkvb, vtb, M_, QS_, H_, H_);

    flash_mfma<<<dim3(B_ * NH_ * S_ / 128 * NSP_), 512, 0, stream>>>(
        qkvb, qkvb + H_, vtb, mask, opart, mlbuf);

    // h = LN(h + merged_ctx); xbf = bf16(h)
    add_ln_mrg<<<dim3(M_), 256, 0, stream>>>(
        h, opart, opart + (size_t)M_ * H_, mlbuf,
        ln1g + l * H_, ln1b + l * H_, h, xbf);

    const unsigned short* wi_l;
    if (big) wi_l = wi_a + (size_t)l * I_ * H_;
    else {
      wcvt<<<dim3(I_ * H_ / 1024), 256, 0, stream>>>(Wi + (size_t)l * I_ * H_, wbuf);
      wi_l = wbuf;
    }
    gemm256<1><<<dim3((M_ / 256) * (I_ / 256)), 512, 0, stream>>>(
        xbf, wi_l, bi + l * I_, nullptr, midbf, M_, I_, H_);

    const unsigned short* wo_l;
    if (big) wo_l = wo_a + (size_t)l * H_ * I_;
    else {
      wcvt<<<dim3(H_ * I_ / 1024), 256, 0, stream>>>(Wo + (size_t)l * H_ * I_, wbuf);
      wo_l = wbuf;
    }
    // MLP2 split-K x2 (bf16 partials): z=0 half (+bias) -> opart[0], z=1 -> opart[1]
    gemm_bt<4><<<dim3(M_ / 128, H_ / 128, 2), 256, 0, stream>>>(
        midbf, wo_l, bo + l * H_, nullptr, opart, nullptr, M_, H_, I_, I_ / 2);

    // h = LN(h + p0 + p1); xbf = bf16(h)
    add_ln<<<dim3(M_), 256, 0, stream>>>(
        h, opart, opart + (size_t)M_ * H_,
        ln2g + l * H_, ln2b + l * H_, h, xbf);
  }

  add_ln<<<dim3(M_), 256, 0, stream>>>(h, nullptr, nullptr, lnfg, lnfb, nullptr, xbf);
  const unsigned short* wlm_l;
  if (big) wlm_l = wlm_a;
  else {
    wcvt<<<dim3(V_ * H_ / 1024), 256, 0, stream>>>(Wlm, wbuf);
    wlm_l = wbuf;
  }
  gemm256<0><<<dim3((M_ / 256) * (V_ / 256)), 512, 0, stream>>>(
      xbf, wlm_l, nullptr, out, nullptr, M_, V_, H_);
}

// Round 22
// 2770.965 us; speedup vs baseline: 1.0641x; 1.0184x over previous
//
#include <hip/hip_runtime.h>
#include <hip/hip_bf16.h>

#define V_ 32000
#define H_ 1024
#define NH_ 16
#define I_ 4096
#define L_ 8
#define B_ 2
#define S_ 2048
#define DH_ 64
#define M_ 4096   // B_*S_
#define QS_ 3072  // fused QKV row stride
#define NSP_ 2    // flash split-KV factor

typedef __attribute__((ext_vector_type(4))) float f32x4;
typedef __attribute__((ext_vector_type(8))) short s16x8;

#define BARRIER() do { asm volatile("" ::: "memory"); __builtin_amdgcn_s_barrier(); asm volatile("" ::: "memory"); } while (0)
#define SCHEDB()  __builtin_amdgcn_sched_barrier(0)

__device__ __forceinline__ unsigned short f2b(float f) {
  union { float f; unsigned u; } x; x.f = f;
  return (unsigned short)((x.u + 0x7FFFu + ((x.u >> 16) & 1u)) >> 16);
}
__device__ __forceinline__ float b2f(unsigned short u) {
  union { float f; unsigned u; } x; x.u = ((unsigned)u) << 16; return x.f;
}

__device__ __forceinline__ void gl_lds16(const unsigned short* g, unsigned short* l) {
  __builtin_amdgcn_global_load_lds(
      (__attribute__((address_space(1))) const void*)g,
      (__attribute__((address_space(3))) void*)l, 16, 0, 0);
}

// ---------------- weight f32 -> bf16 flat convert ------------------------------
__global__ __launch_bounds__(256) void wcvt(const float* __restrict__ src,
                                            unsigned short* __restrict__ dst) {
  size_t i = ((size_t)blockIdx.x * 256 + threadIdx.x) * 4;
  float4 v = *(const float4*)(src + i);
  ushort4 b;
  b.x = f2b(v.x); b.y = f2b(v.y); b.z = f2b(v.z); b.w = f2b(v.w);
  *(ushort4*)(dst + i) = b;
}

// concat per-layer Wq|Wk|Wv (each [H][H]) -> dst [l][3H][H] bf16 (all layers)
__global__ __launch_bounds__(256) void qkvcat_all(const float* __restrict__ q,
                                                  const float* __restrict__ k,
                                                  const float* __restrict__ v,
                                                  unsigned short* __restrict__ dst) {
  size_t i = ((size_t)blockIdx.x * 256 + threadIdx.x) * 4;
  size_t l = i / (3u * H_ * H_);
  size_t r = i - l * (3u * H_ * H_);
  const float* s; size_t off;
  if (r < (size_t)H_ * H_)          { s = q; off = l * H_ * H_ + r; }
  else if (r < 2u * H_ * H_)        { s = k; off = l * H_ * H_ + r - (size_t)H_ * H_; }
  else                              { s = v; off = l * H_ * H_ + r - 2u * H_ * H_; }
  float4 vv = *(const float4*)(s + off);
  ushort4 b;
  b.x = f2b(vv.x); b.y = f2b(vv.y); b.z = f2b(vv.z); b.w = f2b(vv.w);
  *(ushort4*)(dst + i) = b;
}

// concat per-layer Wq|Wk|Wv for ONE layer -> dst [3H][H] bf16 (fallback path)
__global__ __launch_bounds__(256) void qkvcat(const float* __restrict__ q,
                                              const float* __restrict__ k,
                                              const float* __restrict__ v,
                                              unsigned short* __restrict__ dst) {
  int i = (blockIdx.x * 256 + threadIdx.x) * 4;
  const float* s; int off;
  if (i < H_ * H_)          { s = q; off = i; }
  else if (i < 2 * H_ * H_) { s = k; off = i - H_ * H_; }
  else                      { s = v; off = i - 2 * H_ * H_; }
  float4 vv = *(const float4*)(s + off);
  ushort4 b;
  b.x = f2b(vv.x); b.y = f2b(vv.y); b.z = f2b(vv.z); b.w = f2b(vv.w);
  *(ushort4*)(dst + i) = b;
}

// concat biases bq|bk|bv per layer -> [L][3H] f32
__global__ __launch_bounds__(256) void bcat(const float* __restrict__ bq,
                                            const float* __restrict__ bk,
                                            const float* __restrict__ bv,
                                            float* __restrict__ dst) {
  int i = blockIdx.x * 256 + threadIdx.x;       // L_*3*H_ total
  int l = i / (3 * H_), r = i - l * 3 * H_;
  int p = r >> 10, c = r & (H_ - 1);
  const float* s = (p == 0) ? bq : ((p == 1) ? bk : bv);
  dst[i] = s[l * H_ + c];
}

// ---------------- embedding: xbf = bf16(tok[ids] + pos) -----------------------
__global__ __launch_bounds__(256) void embed_kernel(
    const int* __restrict__ ids, const float* __restrict__ tok,
    const float* __restrict__ pos, unsigned short* __restrict__ xbf)
{
  int row = blockIdx.x;
  int c4 = threadIdx.x;
  int id = ids[row];
  int s = row & (S_ - 1);
  float4 tv = ((const float4*)(tok + (size_t)id * H_))[c4];
  float4 pv = ((const float4*)(pos + (size_t)s * H_))[c4];
  ushort4 b;
  b.x = f2b(tv.x + pv.x); b.y = f2b(tv.y + pv.y);
  b.z = f2b(tv.z + pv.z); b.w = f2b(tv.w + pv.w);
  ((ushort4*)(xbf + (size_t)row * H_))[c4] = b;
}

// ---------------- 128x128 GEMM v2: dbuf, 1 barrier/K-step, chunk-XOR swizzle --
// EPI 0: f32 out + bias.  EPI 1: gelu(x+bias) -> bf16.  EPI 2: bias -> bf16.
// EPI 3: QKV fused: Q/K cols -> bf16 at stride N; V cols -> transposed into vt.
// EPI 4: bf16 partial at z*M*N offset into outb (bias only z==0).
template<int EPI>
__global__ __launch_bounds__(256) void gemm_bt(
    const unsigned short* __restrict__ A, const unsigned short* __restrict__ Wb,
    const float* __restrict__ bias, float* __restrict__ outf,
    unsigned short* __restrict__ outb, unsigned short* __restrict__ vt,
    int M, int N, int K, int ksz)
{
  __shared__ unsigned short As[2][128][32];
  __shared__ unsigned short Bs[2][128][32];
  int t = threadIdx.x;
  int lane = t & 63, wid = t >> 6;
  int m0 = blockIdx.x * 128, n0 = blockIdx.y * 128;
  int z = blockIdx.z;
  int koff = z * ksz;
  const float* bz = (z == 0) ? bias : nullptr;
  if (EPI == 0) outf += (size_t)z * M * N;
  int wm = (wid >> 1) * 64, wn = (wid & 1) * 64;
  int fr = lane & 15, hi = lane >> 4;
  int lrow = lane >> 2;
  int lcolsw = (((lane & 3) ^ (lrow & 3)) * 8);  // inverse-swizzled source col
  int ke = ((hi ^ (fr & 3)) * 8);                // swizzled read col (elems)

  f32x4 acc[4][4] = {};

  const unsigned short* Abase = A  + (size_t)(m0 + wid * 32 + lrow) * K + lcolsw;
  const unsigned short* Bbase = Wb + (size_t)(n0 + wid * 32 + lrow) * K + lcolsw;

  auto stage = [&](int s, int k0) {
    gl_lds16(Abase + k0,                  &As[s][wid * 32][0]);
    gl_lds16(Abase + k0 + (size_t)16 * K, &As[s][wid * 32 + 16][0]);
    gl_lds16(Bbase + k0,                  &Bs[s][wid * 32][0]);
    gl_lds16(Bbase + k0 + (size_t)16 * K, &Bs[s][wid * 32 + 16][0]);
  };

  stage(0, koff);

  int cur = 0;
  for (int k0 = koff; k0 < koff + ksz; k0 += 32) {
    asm volatile("s_waitcnt vmcnt(0)" ::: "memory");   // tile cur landed
    BARRIER();
    if (k0 + 32 < koff + ksz) stage(cur ^ 1, k0 + 32); // full K-step of lead time
    SCHEDB();
    s16x8 af[4], bfr[4];
    #pragma unroll
    for (int i = 0; i < 4; ++i) af[i]  = *(const s16x8*)(&As[cur][wm + i * 16 + fr][ke]);
    #pragma unroll
    for (int j = 0; j < 4; ++j) bfr[j] = *(const s16x8*)(&Bs[cur][wn + j * 16 + fr][ke]);
    #pragma unroll
    for (int i = 0; i < 4; ++i)
      #pragma unroll
      for (int j = 0; j < 4; ++j)
        acc[i][j] = __builtin_amdgcn_mfma_f32_16x16x32_bf16(af[i], bfr[j], acc[i][j], 0, 0, 0);
    cur ^= 1;
  }

  int fq = lane >> 4;
  if (EPI == 3) {
    #pragma unroll
    for (int i = 0; i < 4; ++i) {
      #pragma unroll
      for (int j = 0; j < 4; ++j) {
        int col = n0 + wn + j * 16 + fr;
        int row0_ = m0 + wm + i * 16 + fq * 4;
        float bcol = bz ? bz[col] : 0.f;
        if (col < 2 * H_) {
          #pragma unroll
          for (int r = 0; r < 4; ++r)
            outb[(size_t)(row0_ + r) * N + col] = f2b(acc[i][j][r] + bcol);
        } else {
          int d = col - 2 * H_;
          int bh = (row0_ >> 11) * NH_ + (d >> 6);
          int s0 = row0_ & (S_ - 1);
          ushort4 pk;
          pk.x = f2b(acc[i][j][0] + bcol);
          pk.y = f2b(acc[i][j][1] + bcol);
          pk.z = f2b(acc[i][j][2] + bcol);
          pk.w = f2b(acc[i][j][3] + bcol);
          *(ushort4*)(vt + ((size_t)bh * DH_ + (d & 63)) * S_ + s0) = pk;
        }
      }
    }
    return;
  }
  #pragma unroll
  for (int i = 0; i < 4; ++i) {
    #pragma unroll
    for (int j = 0; j < 4; ++j) {
      #pragma unroll
      for (int r = 0; r < 4; ++r) {
        int row = m0 + wm + i * 16 + fq * 4 + r;
        int col = n0 + wn + j * 16 + fr;
        float v = acc[i][j][r] + (bz ? bz[col] : 0.f);
        if (EPI == 0) {
          outf[(size_t)row * N + col] = v;
        } else if (EPI == 1) {
          float ge = 0.5f * v * (1.0f + erff(v * 0.70710678118f));
          outb[(size_t)row * N + col] = f2b(ge);
        } else if (EPI == 4) {
          outb[(size_t)z * M * N + (size_t)row * N + col] = f2b(v);
        } else {
          outb[(size_t)row * N + col] = f2b(v);
        }
      }
    }
  }
}

// ---------------- 256x256 GEMM (r8-proven config: distributed staging) --------
template<int EPI>
__global__ __launch_bounds__(512, 2) void gemm256(
    const unsigned short* __restrict__ A, const unsigned short* __restrict__ Wb,
    const float* __restrict__ bias, float* __restrict__ outf,
    unsigned short* __restrict__ outb, int M, int N, int K)
{
  __shared__ unsigned short ASm[2][16384];   // [slot][256 rows x 64 k]
  __shared__ unsigned short BSm[2][16384];

  const int t = threadIdx.x;
  const int lane = t & 63, wid = t >> 6;
  const int wm = wid >> 2, wn = wid & 3;          // 2 x 4 wave grid
  const int fr = lane & 15, hi = lane >> 4;

  const int Nt = N >> 8;
  const int nwg = gridDim.x;
  const int cpx = nwg >> 3;
  int bid = (int)blockIdx.x;
  int swz = (bid & 7) * cpx + (bid >> 3);
  int band = swz / (4 * Nt);
  int rem = swz - band * (4 * Nt);
  const int m0 = (band * 4 + (rem & 3)) << 8;
  const int n0 = (rem >> 2) << 8;

  const int NT = K >> 6;

  const int srow = lane >> 3;
  const int scol = ((lane & 7) ^ srow) << 3;
  const int ch0 = wid * 2;

  const int axorb = (fr & 7) << 4;
  const int koe0 = ((hi * 16) ^ axorb) >> 1;
  const int koe1 = (((hi * 16) | 64) ^ axorb) >> 1;

  f32x4 acc[8][4] = {};

  auto stage_half = [&](int slot, int h, int k0) {
    if (h < 2) {
      const unsigned short* src =
          A + (size_t)(m0 + h * 128 + ch0 * 8 + srow) * K + k0 + scol;
      unsigned short* dst = &ASm[slot][(h * 128 + ch0 * 8) * 64];
      gl_lds16(src, dst);
      gl_lds16(src + (size_t)8 * K, dst + 8 * 64);
    } else {
      const unsigned short* src =
          Wb + (size_t)(n0 + (h - 2) * 128 + ch0 * 8 + srow) * K + k0 + scol;
      unsigned short* dst = &BSm[slot][((h - 2) * 128 + ch0 * 8) * 64];
      gl_lds16(src, dst);
      gl_lds16(src + (size_t)8 * K, dst + 8 * 64);
    }
  };

  // prologue: tile0 -> slot0 (B first for HBM cover, then A)
  stage_half(0, 2, 0); stage_half(0, 3, 0); stage_half(0, 0, 0); stage_half(0, 1, 0);

  s16x8 af0[4][2], af1[4][2], bfv[4][2];

  for (int T = 0; T < NT; ++T) {
    const int s = T & 1;
    const int k1 = (T + 1) << 6;
    const bool more = (T + 1 < NT);

    asm volatile("s_waitcnt vmcnt(0)" ::: "memory");   // tile T fully landed
    BARRIER();

    const unsigned short* As_ = ASm[s];
    const unsigned short* Bs_ = BSm[s];

    // ---- R0: af0 (m0-3) + all bfv ; stage B-half0(T+1) ----
    #pragma unroll
    for (int mi = 0; mi < 4; ++mi) {
      const unsigned short* p = As_ + (wm * 128 + mi * 16 + fr) * 64;
      af0[mi][0] = *(const s16x8*)(p + koe0);
      af0[mi][1] = *(const s16x8*)(p + koe1);
    }
    #pragma unroll
    for (int nj = 0; nj < 4; ++nj) {
      const unsigned short* p = Bs_ + (wn * 64 + nj * 16 + fr) * 64;
      bfv[nj][0] = *(const s16x8*)(p + koe0);
      bfv[nj][1] = *(const s16x8*)(p + koe1);
    }
    if (more) stage_half(s ^ 1, 2, k1);
    SCHEDB();
    __builtin_amdgcn_s_setprio(1);
    #pragma unroll
    for (int mi = 0; mi < 4; ++mi)
      #pragma unroll
      for (int nj = 0; nj < 2; ++nj) {
        acc[mi][nj] = __builtin_amdgcn_mfma_f32_16x16x32_bf16(af0[mi][0], bfv[nj][0], acc[mi][nj], 0, 0, 0);
        acc[mi][nj] = __builtin_amdgcn_mfma_f32_16x16x32_bf16(af0[mi][1], bfv[nj][1], acc[mi][nj], 0, 0, 0);
      }
    __builtin_amdgcn_s_setprio(0);
    SCHEDB();

    // ---- R2: af1 (m4-7) ; stage B-half1(T+1) ----
    #pragma unroll
    for (int mi = 0; mi < 4; ++mi) {
      const unsigned short* p = As_ + (wm * 128 + (mi + 4) * 16 + fr) * 64;
      af1[mi][0] = *(const s16x8*)(p + koe0);
      af1[mi][1] = *(const s16x8*)(p + koe1);
    }
    if (more) stage_half(s ^ 1, 3, k1);
    SCHEDB();
    __builtin_amdgcn_s_setprio(1);
    #pragma unroll
    for (int mi = 0; mi < 4; ++mi)
      #pragma unroll
      for (int nj = 2; nj < 4; ++nj) {
        acc[mi][nj] = __builtin_amdgcn_mfma_f32_16x16x32_bf16(af0[mi][0], bfv[nj][0], acc[mi][nj], 0, 0, 0);
        acc[mi][nj] = __builtin_amdgcn_mfma_f32_16x16x32_bf16(af0[mi][1], bfv[nj][1], acc[mi][nj], 0, 0, 0);
      }
    __builtin_amdgcn_s_setprio(0);
    SCHEDB();

    // ---- stage A-half0(T+1) ; G2: m4-7 x n2-3 ----
    if (more) stage_half(s ^ 1, 0, k1);
    SCHEDB();
    __builtin_amdgcn_s_setprio(1);
    #pragma unroll
    for (int mi = 0; mi < 4; ++mi)
      #pragma unroll
      for (int nj = 2; nj < 4; ++nj) {
        acc[mi + 4][nj] = __builtin_amdgcn_mfma_f32_16x16x32_bf16(af1[mi][0], bfv[nj][0], acc[mi + 4][nj], 0, 0, 0);
        acc[mi + 4][nj] = __builtin_amdgcn_mfma_f32_16x16x32_bf16(af1[mi][1], bfv[nj][1], acc[mi + 4][nj], 0, 0, 0);
      }
    __builtin_amdgcn_s_setprio(0);
    SCHEDB();

    // ---- stage A-half1(T+1) ; G3: m4-7 x n0-1 ----
    if (more) stage_half(s ^ 1, 1, k1);
    SCHEDB();
    __builtin_amdgcn_s_setprio(1);
    #pragma unroll
    for (int mi = 0; mi < 4; ++mi)
      #pragma unroll
      for (int nj = 0; nj < 2; ++nj) {
        acc[mi + 4][nj] = __builtin_amdgcn_mfma_f32_16x16x32_bf16(af1[mi][0], bfv[nj][0], acc[mi + 4][nj], 0, 0, 0);
        acc[mi + 4][nj] = __builtin_amdgcn_mfma_f32_16x16x32_bf16(af1[mi][1], bfv[nj][1], acc[mi + 4][nj], 0, 0, 0);
      }
    __builtin_amdgcn_s_setprio(0);
  }

  #pragma unroll
  for (int mi = 0; mi < 8; ++mi) {
    #pragma unroll
    for (int nj = 0; nj < 4; ++nj) {
      #pragma unroll
      for (int r = 0; r < 4; ++r) {
        int row = m0 + wm * 128 + mi * 16 + hi * 4 + r;
        int col = n0 + wn * 64 + nj * 16 + fr;
        float v = acc[mi][nj][r] + (bias ? bias[col] : 0.f);
        if (EPI == 0) {
          outf[(size_t)row * N + col] = v;
        } else if (EPI == 1) {
          float ge = 0.5f * v * (1.0f + erff(v * 0.70710678118f));
          outb[(size_t)row * N + col] = f2b(ge);
        } else {
          outb[(size_t)row * N + col] = f2b(v);
        }
      }
    }
  }
}

// ---------------- MFMA flash attention v7 (bf16 partials) ---------------------
#define KB_ 64
#define SPL_ 1024
__global__ __launch_bounds__(512, 2) void flash_mfma(
    const unsigned short* __restrict__ qb,  // q slice base (stride QS_)
    const unsigned short* __restrict__ kb,  // k slice base (stride QS_)
    const unsigned short* __restrict__ vtb, // [B*NH][DH][S] bf16
    const float* __restrict__ mask,         // [B][S]
    unsigned short* __restrict__ opart,     // [NSP_][M][H] unnormalized bf16
    float2* __restrict__ ml)                // [NSP_][32][S] (m, l)
{
  __shared__ unsigned short K2[2][KB_ * DH_];   // [slot][kv][d] swizzled
  __shared__ unsigned short V2[2][DH_ * KB_];   // [slot][d][kv] swizzled
  __shared__ unsigned short Ps[8][16][72];      // per-wave P [q][kv], padded
  __shared__ float xpose[8][16];                // per-wave q-transpose bounce

  const float LOG2E = 1.4426950408889634f;
  const float SCL = 0.125f * LOG2E;
  int t = threadIdx.x, lane = t & 63, wid = t >> 6;   // wid 0..7
  int blk = blockIdx.x;
  int bh = blk & 31;                    // bh fastest => same head -> same XCD
  int rest = blk >> 5;
  int qt = rest & 15, sp = rest >> 4;   // sp 0..1
  int b = bh >> 4, hh = bh & 15;
  int row0 = b * S_ + qt * 128 + wid * 16;
  int fr = lane & 15, hi = lane >> 4;
  const float* mrow = mask + (size_t)b * S_;
  const int kv0 = sp * SPL_;

  s16x8 qf[2];
  {
    const unsigned short* qrow = qb + (size_t)(row0 + fr) * QS_ + hh * DH_;
    qf[0] = *(const s16x8*)(qrow + hi * 8);
    qf[1] = *(const s16x8*)(qrow + 32 + hi * 8);
  }

  float m_run = -3.0e38f, l_run = 0.f;   // per q=fr (replicated over hi)
  f32x4 octx[4] = {};

  const unsigned short* Kbase = kb + (size_t)b * S_ * QS_ + hh * DH_;
  const unsigned short* Vbase = vtb + (size_t)bh * DH_ * S_;

  int crow = lane >> 3;
  int scol = ((lane & 7) ^ crow) * 8;

  auto stage = [&](int slot, int t0) {
    gl_lds16(Kbase + (size_t)(t0 + wid * 8 + crow) * QS_ + scol, &K2[slot][wid * 512]);
    gl_lds16(Vbase + (size_t)(wid * 8 + crow) * S_ + t0 + scol,  &V2[slot][wid * 512]);
  };

  stage(0, kv0);

  const int swz = (fr & 7) * 8;

  int tt = 0;
  for (int t0 = kv0; t0 < kv0 + SPL_; t0 += KB_, ++tt) {
    int slot = tt & 1;
    __syncthreads();
    if (t0 + KB_ < kv0 + SPL_) stage(slot ^ 1, t0 + KB_);

    // QK^T swapped: sacc[g] = mfma(K rows, Q) -> C[m=kv][n=q]
    f32x4 sacc[4] = {};
    #pragma unroll
    for (int g = 0; g < 4; ++g) {
      #pragma unroll
      for (int i = 0; i < 2; ++i) {
        s16x8 kf = *(const s16x8*)(&K2[slot][(g * 16 + fr) * 64 + ((i * 32 + hi * 8) ^ swz)]);
        sacc[g] = __builtin_amdgcn_mfma_f32_16x16x32_bf16(kf, qf[i], sacc[g], 0, 0, 0);
      }
    }

    // scale + mask in place; track tile max
    float tm = -3.0e38f;
    #pragma unroll
    for (int g = 0; g < 4; ++g) {
      float4 mq = *(const float4*)(mrow + t0 + g * 16 + hi * 4);
      #pragma unroll
      for (int r = 0; r < 4; ++r) {
        float mk = (1.0f - ((const float*)&mq)[r]) * (-10000.0f * LOG2E);
        float v = sacc[g][r] * SCL + mk;
        sacc[g][r] = v;
        tm = fmaxf(tm, v);
      }
    }
    tm = fmaxf(tm, __shfl_xor(tm, 16));
    tm = fmaxf(tm, __shfl_xor(tm, 32));

    if (!__all(tm <= m_run + 8.0f)) {
      float mn = fmaxf(m_run, tm);
      float corr = exp2f(m_run - mn);
      m_run = mn; l_run *= corr;
      xpose[wid][fr] = corr;
      float cr0 = xpose[wid][hi * 4 + 0];
      float cr1 = xpose[wid][hi * 4 + 1];
      float cr2 = xpose[wid][hi * 4 + 2];
      float cr3 = xpose[wid][hi * 4 + 3];
      #pragma unroll
      for (int dg = 0; dg < 4; ++dg) {
        octx[dg][0] *= cr0; octx[dg][1] *= cr1;
        octx[dg][2] *= cr2; octx[dg][3] *= cr3;
      }
    }

    // exp + pack + stream to Ps per group (short live ranges)
    float ps = 0.f;
    #pragma unroll
    for (int g = 0; g < 4; ++g) {
      float p0 = exp2f(sacc[g][0] - m_run);
      float p1 = exp2f(sacc[g][1] - m_run);
      float p2 = exp2f(sacc[g][2] - m_run);
      float p3 = exp2f(sacc[g][3] - m_run);
      ps += (p0 + p1) + (p2 + p3);
      uint2 pk;
      pk.x = (unsigned)f2b(p0) | ((unsigned)f2b(p1) << 16);
      pk.y = (unsigned)f2b(p2) | ((unsigned)f2b(p3) << 16);
      *(uint2*)(&Ps[wid][fr][g * 16 + hi * 4]) = pk;
    }
    ps += __shfl_xor(ps, 16);
    ps += __shfl_xor(ps, 32);
    l_run += ps;

    #pragma unroll
    for (int kc = 0; kc < 2; ++kc) {
      s16x8 pf = *(const s16x8*)(&Ps[wid][fr][kc * 32 + hi * 8]);
      #pragma unroll
      for (int dg = 0; dg < 4; ++dg) {
        s16x8 vf2 = *(const s16x8*)(&V2[slot][(dg * 16 + fr) * 64 + ((kc * 32 + hi * 8) ^ swz)]);
        octx[dg] = __builtin_amdgcn_mfma_f32_16x16x32_bf16(pf, vf2, octx[dg], 0, 0, 0);
      }
    }
  }

  unsigned short* ob = opart + (size_t)sp * M_ * H_;
  #pragma unroll
  for (int dg = 0; dg < 4; ++dg) {
    size_t base = (size_t)(row0 + hi * 4) * H_ + hh * DH_ + dg * 16 + fr;
    ob[base]              = f2b(octx[dg][0]);
    ob[base + H_]         = f2b(octx[dg][1]);
    ob[base + 2 * H_]     = f2b(octx[dg][2]);
    ob[base + 3 * H_]     = f2b(octx[dg][3]);
  }
  if (hi == 0)
    ml[((size_t)sp * 32 + bh) * S_ + qt * 128 + wid * 16 + fr] =
        make_float2(m_run, l_run);
}

// -------- fused 2-way attn-merge + bf16 residual + LayerNorm (POST-LN) --------
__global__ __launch_bounds__(256) void add_ln_mrg(
    const unsigned short* __restrict__ x, const unsigned short* __restrict__ o0,
    const unsigned short* __restrict__ o1, const float2* __restrict__ ml,
    const float* __restrict__ g, const float* __restrict__ bb,
    unsigned short* __restrict__ outb)
{
  __shared__ float a1[4], a2[4];
  int row = blockIdx.x, t = threadIdx.x;
  int hh = t >> 4;                     // 4 cols per thread, 64 cols per head
  int bh = (row >> 11) * NH_ + hh;
  int q = row & (S_ - 1);
  float2 a = ml[(size_t)bh * S_ + q];
  float2 c = ml[(size_t)(32 + bh) * S_ + q];
  float m = fmaxf(a.x, c.x);
  float w0 = exp2f(a.x - m), w1 = exp2f(c.x - m);
  float inv0 = 1.0f / (a.y * w0 + c.y * w1);
  ushort4 xv = ((const ushort4*)(x + (size_t)row * H_))[t];
  ushort4 b0 = ((const ushort4*)(o0 + (size_t)row * H_))[t];
  ushort4 b1 = ((const ushort4*)(o1 + (size_t)row * H_))[t];
  float4 v;
  v.x = b2f(xv.x) + (b2f(b0.x) * w0 + b2f(b1.x) * w1) * inv0;
  v.y = b2f(xv.y) + (b2f(b0.y) * w0 + b2f(b1.y) * w1) * inv0;
  v.z = b2f(xv.z) + (b2f(b0.z) * w0 + b2f(b1.z) * w1) * inv0;
  v.w = b2f(xv.w) + (b2f(b0.w) * w0 + b2f(b1.w) * w1) * inv0;
  float s1 = v.x + v.y + v.z + v.w;
  float s2 = v.x * v.x + v.y * v.y + v.z * v.z + v.w * v.w;
  #pragma unroll
  for (int d = 32; d; d >>= 1) { s1 += __shfl_xor(s1, d); s2 += __shfl_xor(s2, d); }
  if ((t & 63) == 0) { a1[t >> 6] = s1; a2[t >> 6] = s2; }
  __syncthreads();
  s1 = a1[0] + a1[1] + a1[2] + a1[3];
  s2 = a2[0] + a2[1] + a2[2] + a2[3];
  float mean = s1 * (1.0f / H_);
  float var = s2 * (1.0f / H_) - mean * mean;
  float inv = rsqrtf(var + 1e-5f);
  float4 gv = ((const float4*)g)[t];
  float4 bv = ((const float4*)bb)[t];
  ushort4 ob;
  ob.x = f2b((v.x - mean) * inv * gv.x + bv.x);
  ob.y = f2b((v.y - mean) * inv * gv.y + bv.y);
  ob.z = f2b((v.z - mean) * inv * gv.z + bv.z);
  ob.w = f2b((v.w - mean) * inv * gv.w + bv.w);
  ((ushort4*)(outb + (size_t)row * H_))[t] = ob;   // POST-LN residual (bf16)
}

// -------- fused bf16 residual (+y +y2 bf16) LayerNorm (POST-LN) ---------------
__global__ __launch_bounds__(256) void add_ln(
    const unsigned short* __restrict__ x, const unsigned short* __restrict__ y,
    const unsigned short* __restrict__ y2,
    const float* __restrict__ g, const float* __restrict__ bb,
    unsigned short* __restrict__ outb)
{
  __shared__ float a1[4], a2[4];
  int row = blockIdx.x, t = threadIdx.x;
  ushort4 xv = ((const ushort4*)(x + (size_t)row * H_))[t];
  float4 v;
  v.x = b2f(xv.x); v.y = b2f(xv.y); v.z = b2f(xv.z); v.w = b2f(xv.w);
  if (y) {
    ushort4 u = ((const ushort4*)(y + (size_t)row * H_))[t];
    v.x += b2f(u.x); v.y += b2f(u.y); v.z += b2f(u.z); v.w += b2f(u.w);
  }
  if (y2) {
    ushort4 u = ((const ushort4*)(y2 + (size_t)row * H_))[t];
    v.x += b2f(u.x); v.y += b2f(u.y); v.z += b2f(u.z); v.w += b2f(u.w);
  }
  float s1 = v.x + v.y + v.z + v.w;
  float s2 = v.x * v.x + v.y * v.y + v.z * v.z + v.w * v.w;
  #pragma unroll
  for (int d = 32; d; d >>= 1) { s1 += __shfl_xor(s1, d); s2 += __shfl_xor(s2, d); }
  if ((t & 63) == 0) { a1[t >> 6] = s1; a2[t >> 6] = s2; }
  __syncthreads();
  s1 = a1[0] + a1[1] + a1[2] + a1[3];
  s2 = a2[0] + a2[1] + a2[2] + a2[3];
  float mean = s1 * (1.0f / H_);
  float var = s2 * (1.0f / H_) - mean * mean;
  float inv = rsqrtf(var + 1e-5f);
  float4 gv = ((const float4*)g)[t];
  float4 bv = ((const float4*)bb)[t];
  ushort4 ob;
  ob.x = f2b((v.x - mean) * inv * gv.x + bv.x);
  ob.y = f2b((v.y - mean) * inv * gv.y + bv.y);
  ob.z = f2b((v.z - mean) * inv * gv.z + bv.z);
  ob.w = f2b((v.w - mean) * inv * gv.w + bv.w);
  ((ushort4*)(outb + (size_t)row * H_))[t] = ob;   // POST-LN residual (bf16)
}

// ------------------------------- launcher -------------------------------------
extern "C" void kernel_launch(void* const* d_in, const int* in_sizes, int n_in,
                              void* d_out, int out_size, void* d_ws, size_t ws_size,
                              hipStream_t stream) {
  const int*   ids  = (const int*)d_in[0];
  const float* mask = (const float*)d_in[1];
  const float* tok  = (const float*)d_in[2];
  const float* pos  = (const float*)d_in[3];
  const float* Wq   = (const float*)d_in[4];
  const float* bq   = (const float*)d_in[5];
  const float* Wk   = (const float*)d_in[6];
  const float* bk   = (const float*)d_in[7];
  const float* Wv   = (const float*)d_in[8];
  const float* bv   = (const float*)d_in[9];
  const float* Wi   = (const float*)d_in[10];
  const float* bi   = (const float*)d_in[11];
  const float* Wo   = (const float*)d_in[12];
  const float* bo   = (const float*)d_in[13];
  const float* ln1g = (const float*)d_in[14];
  const float* ln1b = (const float*)d_in[15];
  const float* ln2g = (const float*)d_in[16];
  const float* ln2b = (const float*)d_in[17];
  const float* lnfg = (const float*)d_in[18];
  const float* lnfb = (const float*)d_in[19];
  const float* Wlm  = (const float*)d_in[20];
  float* out = (float*)d_out;

  char* w = (char*)d_ws;
  size_t off = 0;
  auto alloc = [&](size_t bytes) { void* p = w + off; off = (off + bytes + 255) & ~(size_t)255; return p; };
  unsigned short* qkvb  = (unsigned short*)alloc((size_t)M_ * QS_ * 2);
  unsigned short* vtb   = (unsigned short*)alloc((size_t)B_ * NH_ * DH_ * S_ * 2);
  unsigned short* xbf   = (unsigned short*)alloc((size_t)M_ * H_ * 2);
  unsigned short* midbf = (unsigned short*)alloc((size_t)M_ * I_ * 2);
  float* bqkv  = (float*)alloc((size_t)L_ * QS_ * 4);
  unsigned short* opart = (unsigned short*)alloc((size_t)NSP_ * M_ * H_ * 2);  // bf16 partials
  float2* mlbuf = (float2*)alloc((size_t)NSP_ * 32 * S_ * 8);

  size_t wqkv_b = (size_t)L_ * 3 * H_ * H_ * 2;
  size_t wi_bb  = (size_t)L_ * I_ * H_ * 2;
  size_t wo_bb  = (size_t)L_ * H_ * I_ * 2;
  size_t wlm_bb = (size_t)V_ * H_ * 2;
  bool big = (ws_size - off) >= (wqkv_b + wi_bb + wo_bb + wlm_bb + 4 * 256);

  unsigned short *wqkv, *wi_a, *wo_a, *wlm_a, *wbuf = nullptr;
  if (big) {
    wqkv  = (unsigned short*)alloc(wqkv_b);
    wi_a  = (unsigned short*)alloc(wi_bb);
    wo_a  = (unsigned short*)alloc(wo_bb);
    wlm_a = (unsigned short*)alloc(wlm_bb);
    qkvcat_all<<<dim3((unsigned)((size_t)L_ * 3 * H_ * H_ / 1024)), 256, 0, stream>>>(Wq, Wk, Wv, wqkv);
    wcvt<<<dim3((unsigned)((size_t)L_ * I_ * H_ / 1024)), 256, 0, stream>>>(Wi, wi_a);
    wcvt<<<dim3((unsigned)((size_t)L_ * H_ * I_ / 1024)), 256, 0, stream>>>(Wo, wo_a);
    wcvt<<<dim3((unsigned)((size_t)V_ * H_ / 1024)), 256, 0, stream>>>(Wlm, wlm_a);
  } else {
    wbuf = (unsigned short*)alloc((size_t)V_ * H_ * 2);
  }

  bcat<<<dim3(L_ * QS_ / 256), 256, 0, stream>>>(bq, bk, bv, bqkv);
  embed_kernel<<<dim3(M_), 256, 0, stream>>>(ids, tok, pos, xbf);

  for (int l = 0; l < L_; ++l) {
    const unsigned short* wq_l;
    if (big) wq_l = wqkv + (size_t)l * 3 * H_ * H_;
    else {
      qkvcat<<<dim3(3 * H_ * H_ / 1024), 256, 0, stream>>>(
          Wq + (size_t)l * H_ * H_, Wk + (size_t)l * H_ * H_, Wv + (size_t)l * H_ * H_, wbuf);
      wq_l = wbuf;
    }
    // fused QKV GEMM: Q/K -> qkvb (bf16, stride QS_), V -> vtb transposed
    gemm_bt<3><<<dim3(M_ / 128, QS_ / 128, 1), 256, 0, stream>>>(
        xbf, wq_l, bqkv + (size_t)l * QS_, nullptr, qkvb, vtb, M_, QS_, H_, H_);

    flash_mfma<<<dim3(B_ * NH_ * S_ / 128 * NSP_), 512, 0, stream>>>(
        qkvb, qkvb + H_, vtb, mask, opart, mlbuf);

    // xbf = LN(xbf + merged_ctx)  (bf16 residual)
    add_ln_mrg<<<dim3(M_), 256, 0, stream>>>(
        xbf, opart, opart + (size_t)M_ * H_, mlbuf,
        ln1g + l * H_, ln1b + l * H_, xbf);

    const unsigned short* wi_l;
    if (big) wi_l = wi_a + (size_t)l * I_ * H_;
    else {
      wcvt<<<dim3(I_ * H_ / 1024), 256, 0, stream>>>(Wi + (size_t)l * I_ * H_, wbuf);
      wi_l = wbuf;
    }
    gemm256<1><<<dim3((M_ / 256) * (I_ / 256)), 512, 0, stream>>>(
        xbf, wi_l, bi + l * I_, nullptr, midbf, M_, I_, H_);

    const unsigned short* wo_l;
    if (big) wo_l = wo_a + (size_t)l * H_ * I_;
    else {
      wcvt<<<dim3(H_ * I_ / 1024), 256, 0, stream>>>(Wo + (size_t)l * H_ * I_, wbuf);
      wo_l = wbuf;
    }
    // MLP2 split-K x2 (bf16 partials): z=0 half (+bias) -> opart[0], z=1 -> opart[1]
    gemm_bt<4><<<dim3(M_ / 128, H_ / 128, 2), 256, 0, stream>>>(
        midbf, wo_l, bo + l * H_, nullptr, opart, nullptr, M_, H_, I_, I_ / 2);

    // xbf = LN(xbf + p0 + p1)  (bf16 residual)
    add_ln<<<dim3(M_), 256, 0, stream>>>(
        xbf, opart, opart + (size_t)M_ * H_,
        ln2g + l * H_, ln2b + l * H_, xbf);
  }

  add_ln<<<dim3(M_), 256, 0, stream>>>(xbf, nullptr, nullptr, lnfg, lnfb, xbf);
  const unsigned short* wlm_l;
  if (big) wlm_l = wlm_a;
  else {
    wcvt<<<dim3(V_ * H_ / 1024), 256, 0, stream>>>(Wlm, wbuf);
    wlm_l = wbuf;
  }
  gemm256<0><<<dim3((M_ / 256) * (V_ / 256)), 512, 0, stream>>>(
      xbf, wlm_l, nullptr, out, nullptr, M_, V_, H_);
}